// Round 7
// baseline (1273.336 us; speedup 1.0000x reference)
//
#include <hip/hip_runtime.h>
#include <hip/hip_bf16.h>

typedef unsigned short ushort_t;
typedef __attribute__((ext_vector_type(8))) short short8;
typedef __attribute__((ext_vector_type(4))) float float4v;

__device__ __forceinline__ float bfu(ushort_t u) {
    return __uint_as_float(((unsigned)u) << 16);
}
__device__ __forceinline__ float bfu(unsigned u) {
    return __uint_as_float(u << 16);
}
__device__ __forceinline__ ushort_t f2bf(float f) {
    __hip_bfloat16 h = __float2bfloat16(f);
    return *reinterpret_cast<ushort_t*>(&h);
}
__device__ __forceinline__ unsigned enc_f(float f) {
    unsigned b = __float_as_uint(f);
    return (b & 0x80000000u) ? ~b : (b | 0x80000000u);
}
__device__ __forceinline__ float dec_f(unsigned b) {
    return (b & 0x80000000u) ? __uint_as_float(b & 0x7FFFFFFFu) : __uint_as_float(~b);
}

// ---------------- fused setup: node_enc + zero + combine_w + combine2 + prep_w ----

__global__ __launch_bounds__(256) void setup_kernel(
    const float* __restrict__ x, const float* __restrict__ node_W,
    const float* __restrict__ node_b,
    const float* __restrict__ edge_W, const float* __restrict__ edge_b,
    const float* __restrict__ We, const float* __restrict__ be,
    const float* __restrict__ Wq, const float* __restrict__ bq,
    const float* __restrict__ Wk, const float* __restrict__ bk,
    const float* __restrict__ Wv, const float* __restrict__ bv,
    const float* __restrict__ Wskip, const float* __restrict__ bskip,
    float* __restrict__ h, ushort_t* __restrict__ h_bf,
    int* __restrict__ counts, unsigned* __restrict__ gmax,
    float* __restrict__ Wc, float* __restrict__ bcb,
    float* __restrict__ Wqc_all, float* __restrict__ bias18,
    ushort_t* __restrict__ Wall_arr, float* __restrict__ Wall_bias,
    int O0, int O1, int O2, int O3, int O4, int N) {
    int b = blockIdx.x, t = threadIdx.x;
    if (b < O0) {
        // node encoder
        int idx = b * 256 + t;
        if (idx < N * 64) {
            int n = idx >> 6, c = idx & 63;
            float acc = node_b[c];
#pragma unroll
            for (int j = 0; j < 16; ++j) acc += x[n * 16 + j] * node_W[j * 64 + c];
            h[idx] = acc;
            h_bf[idx] = f2bf(acc);
        }
    } else if (b < O1) {
        int i = (b - O0) * 256 + t;
        if (i < N) counts[i] = 0;
    } else if (b < O2) {
        if (t < 64) gmax[t] = 0u;
    } else if (b < O3) {
        int tid = (b - O2) * 256 + t;
        if (tid < 2048) {
            int l = tid >> 10, d = (tid >> 7) & 7, j = tid & 127;
            float s = 0.f;
            for (int m = 0; m < 64; ++m) s += edge_W[d * 64 + m] * We[l * 8192 + m * 128 + j];
            Wc[l * 1024 + d * 128 + j] = s;
        } else if (tid < 2048 + 256) {
            int u = tid - 2048;
            int l = u >> 7, j = u & 127;
            float s = be[l * 128 + j];
            for (int m = 0; m < 64; ++m) s += edge_b[m] * We[l * 8192 + m * 128 + j];
            bcb[l * 128 + j] = s;
        }
    } else if (b < O4) {
        // combine2: needs Wc/bcb? NO — recompute from edge_W/We directly to avoid dependency:
        // Wqc[l][k][j<16] = 0.125 * sum_c Wq[k][h*64+c] * Wc[d][h*64+c]
        // Wc[d][col] = sum_m edge_W[d*64+m]... wait Wc has K=64 inner. Recompute inline:
        int tid = (b - O3) * 256 + t;
        if (tid < 2304 + 36) {
            int isb = (tid >= 2304);
            int u = isb ? (tid - 2304) : tid;
            int l, k = 0, j;
            if (isb) { l = u / 18; j = u % 18; }
            else { l = u / 1152; int w = u % 1152; k = w / 18; j = w % 18; }
            const float* qrow = isb ? (bq + l * 128) : (Wq + l * 8192 + k * 128);
            float s = 0.f;
            if (j < 16) {
                int hh = j >> 3, d = j & 7;
                // Wc[l][d][hh*64+c] = sum_m edge_W[d][m]*We[l][m][hh*64+c+? ] (col=hh*64+c within 128)
                for (int c = 0; c < 64; ++c) {
                    float wc = 0.f;
                    for (int m = 0; m < 64; ++m)
                        wc += edge_W[d * 64 + m] * We[l * 8192 + m * 128 + (j >> 3) * 64 + c];
                    s += qrow[hh * 64 + c] * wc;
                }
            } else {
                int hh = j - 16;
                for (int c = 0; c < 64; ++c) {
                    float bc = be[l * 128 + hh * 64 + c];
                    for (int m = 0; m < 64; ++m)
                        bc += edge_b[m] * We[l * 8192 + m * 128 + hh * 64 + c];
                    s += qrow[hh * 64 + c] * bc;
                }
            }
            s *= 0.125f;
            if (isb) bias18[l * 18 + j] = s;
            else Wqc_all[l * 1152 + k * 18 + j] = s;
        }
    } else {
        int tid = (b - O4) * 256 + t;
        if (tid < 2 * 28672) {
            int l = tid / 28672, u = tid % 28672;
            int j = u & 7, ln = (u >> 3) & 63, kch = (u >> 9) & 1, ct = u >> 10;
            int nn = ln & 15, quad = ln >> 4;
            int k = kch * 32 + quad * 8 + j;
            int col = ct * 16 + nn;
            float v;
            if (col < 128)      v = Wq[l * 8192 + k * 128 + col];
            else if (col < 256) v = Wk[l * 8192 + k * 128 + col - 128];
            else if (col < 384) v = Wv[l * 8192 + k * 128 + col - 256];
            else                v = Wskip[l * 4096 + k * 64 + col - 384];
            Wall_arr[(size_t)l * 28672 + u] = f2bf(v);
        } else if (tid < 2 * 28672 + 2 * 448) {
            int u = tid - 2 * 28672;
            int l = u / 448, col = u % 448;
            float v;
            if (col < 128)      v = bq[l * 128 + col];
            else if (col < 256) v = bk[l * 128 + col - 128];
            else if (col < 384) v = bv[l * 128 + col - 256];
            else                v = bskip[l * 64 + col - 384];
            Wall_bias[l * 448 + col] = v;
        }
    }
}

// ---------------- CSR build (by dst) ----------------

__global__ void csr_count_kernel(const int* __restrict__ dst, int* __restrict__ counts, int E) {
    int e = blockIdx.x * 256 + threadIdx.x;
    if (e < E) atomicAdd(&counts[dst[e]], 1);
}

__global__ void scan1_kernel(const int* __restrict__ counts, int* __restrict__ rowptr,
                             int* __restrict__ bsums, int N) {
    __shared__ int s[256];
    int t = threadIdx.x, i = blockIdx.x * 256 + t;
    int v = (i < N) ? counts[i] : 0;
    s[t] = v;
    __syncthreads();
    for (int d = 1; d < 256; d <<= 1) {
        int x = (t >= d) ? s[t - d] : 0;
        __syncthreads();
        s[t] += x;
        __syncthreads();
    }
    if (i < N) rowptr[i] = s[t] - v;
    if (t == 255) bsums[blockIdx.x] = s[255];
}

__global__ void scan2_kernel(int* __restrict__ bsums, int nb) {
    __shared__ int s[256];
    int t = threadIdx.x;
    int v = (t < nb) ? bsums[t] : 0;
    s[t] = v;
    __syncthreads();
    for (int d = 1; d < 256; d <<= 1) {
        int x = (t >= d) ? s[t - d] : 0;
        __syncthreads();
        s[t] += x;
        __syncthreads();
    }
    if (t < nb) bsums[t] = s[t] - v;
}

__global__ void scan3_kernel(int* __restrict__ rowptr, const int* __restrict__ bsums,
                             int* __restrict__ cursor, int N, int E) {
    int i = blockIdx.x * 256 + threadIdx.x;
    if (i < N) {
        int r = rowptr[i] + bsums[i >> 8];
        rowptr[i] = r;
        cursor[i] = r;
    }
    if (i == 0) rowptr[N] = E;
}

__global__ void csr_fill_kernel(const int* __restrict__ dst, int* __restrict__ cursor,
                                int* __restrict__ csr, int E) {
    int e = blockIdx.x * 256 + threadIdx.x;
    if (e < E) {
        int pos = atomicAdd(&cursor[dst[e]], 1);
        csr[pos] = e;
    }
}

// ---------------- per-layer: fused qkv-MFMA (y=0) + qc (y=1) ----------------
// qkv row layout (ushort units): q[0..127], then k/v interleaved in pairs:
//   k channel c -> 128 + 4*(c>>1) + (c&1);  v channel c -> 128 + 4*(c>>1) + 2 + (c&1)

__global__ __launch_bounds__(256) void qkvqc_kernel(
    const float* __restrict__ h, const ushort_t* __restrict__ h_bf,
    const ushort_t* __restrict__ Wall_arr, const float* __restrict__ Wall_bias,
    const float* __restrict__ Wqc, const float* __restrict__ bias18,
    ushort_t* __restrict__ qkv, float* __restrict__ outbuf, float* __restrict__ qcbuf, int N) {
    if (blockIdx.y == 0) {
        int wave = threadIdx.x >> 6, lane = threadIdx.x & 63;
        int quad = lane >> 4, nn = lane & 15;
        int n0 = blockIdx.x * 16;
        int node_a = n0 + nn;
        if (node_a >= N) node_a = N - 1;
        const ushort_t* ap = h_bf + (size_t)node_a * 64 + quad * 8;
        short8 a0 = *(const short8*)ap;
        short8 a1 = *(const short8*)(ap + 32);
#pragma unroll
        for (int i = 0; i < 7; ++i) {
            int ct = wave * 7 + i;
            const ushort_t* bp = Wall_arr + ((size_t)(ct * 2) * 64 + lane) * 8;
            short8 b0 = *(const short8*)bp;
            short8 b1 = *(const short8*)(bp + 512);
            float4v c = {0.f, 0.f, 0.f, 0.f};
            c = __builtin_amdgcn_mfma_f32_16x16x32_bf16(a0, b0, c, 0, 0, 0);
            c = __builtin_amdgcn_mfma_f32_16x16x32_bf16(a1, b1, c, 0, 0, 0);
            int col = ct * 16 + nn;
            float bias = Wall_bias[col];
            if (col < 384) {
                int cm;
                if (col < 128) cm = col;
                else if (col < 256) { int cc = col - 128; cm = 128 + ((cc >> 1) << 2) + (cc & 1); }
                else { int cc = col - 256; cm = 128 + ((cc >> 1) << 2) + 2 + (cc & 1); }
                ushort_t* qp = qkv + (size_t)(n0 + quad * 4) * 384 + cm;
#pragma unroll
                for (int r = 0; r < 4; ++r)
                    if (n0 + quad * 4 + r < N) qp[(size_t)r * 384] = f2bf(c[r] + bias);
            } else {
                float* op = outbuf + (size_t)(n0 + quad * 4) * 64 + (col - 384);
#pragma unroll
                for (int r = 0; r < 4; ++r)
                    if (n0 + quad * 4 + r < N) op[(size_t)r * 64] = c[r] + bias;
            }
        }
    } else {
        __shared__ float hs[16 * 64];
        __shared__ float w_s[64 * 18];
        __shared__ float b_s[18];
        int t = threadIdx.x;
        int n0 = blockIdx.x * 16;
        for (int i = t; i < 1152; i += 256) w_s[i] = Wqc[i];
        if (t < 18) b_s[t] = bias18[t];
        for (int i = t; i < 1024; i += 256) {
            int n = n0 + (i >> 6);
            hs[i] = (n < N) ? h[(size_t)n * 64 + (i & 63)] : 0.f;
        }
        __syncthreads();
        for (int o = t; o < 16 * 18; o += 256) {
            int nl = o / 18, j = o % 18;
            int n = n0 + nl;
            if (n < N) {
                float s = b_s[j];
                for (int k = 0; k < 64; ++k) s += hs[nl * 64 + k] * w_s[k * 18 + j];
                qcbuf[(size_t)n * 20 + j] = s;
            }
        }
    }
}

// ---------------- attention: one wave per node, 2 edges/iter, scalarized indices ----

__device__ __forceinline__ void load_idx(const int* __restrict__ csr,
                                         const int* __restrict__ esrc,
                                         int gi, int end, int start,
                                         int& e, int& s, int& v) {
    v = (gi < end);
    int gg = v ? gi : start;
    int ee = csr[gg];
    ee = __builtin_amdgcn_readfirstlane(ee);
    int ss = esrc[ee];
    ss = __builtin_amdgcn_readfirstlane(ss);
    e = ee;
    s = ss;
}

__device__ __forceinline__ void load_data(const ushort_t* __restrict__ qkv,
                                          const float* __restrict__ ea,
                                          int e, int s, int lane,
                                          uint2& kv, float4& a0, float4& a1) {
    kv = *(const uint2*)(qkv + (size_t)s * 384 + 128 + 4 * lane);
    a0 = *(const float4*)(ea + (size_t)e * 8);
    a1 = *(const float4*)(ea + (size_t)e * 8 + 4);
}

__global__ __launch_bounds__(256) void attn_kernel(
    const ushort_t* __restrict__ qkv, const float* __restrict__ qcbuf,
    const float* __restrict__ edge_attr, const int* __restrict__ edge_src,
    const int* __restrict__ rowptr, const int* __restrict__ csr,
    const float* __restrict__ Wc, const float* __restrict__ bcb,
    float* __restrict__ outbuf, int N) {
    __shared__ float Wc_s[1024];
    __shared__ float bc_s[128];
    int t = threadIdx.x;
    for (int i = t; i < 1024; i += 256) Wc_s[i] = Wc[i];
    if (t < 128) bc_s[t] = bcb[t];
    __syncthreads();
    int lane = t & 63, wid = t >> 6;
    int half = lane >> 5, l31 = lane & 31;
    for (int n = blockIdx.x * 4 + wid; n < N; n += gridDim.x * 4) {
        int start = rowptr[n], end = rowptr[n + 1];
        if (end <= start) continue;  // outbuf already holds skip
        const ushort_t* rowq = qkv + (size_t)n * 384;
        unsigned qraw = *(const unsigned*)(rowq + 2 * lane);
        float qx = bfu(qraw & 0xffffu), qy = bfu(qraw >> 16);
        const float4 qcA = *(const float4*)(qcbuf + (size_t)n * 20 + half * 8);
        const float4 qcB = *(const float4*)(qcbuf + (size_t)n * 20 + half * 8 + 4);
        float qb = qcbuf[(size_t)n * 20 + 16 + half];
        float lsum = 0.f, ax = 0.f, ay = 0.f;
        float4 se0 = {0.f, 0.f, 0.f, 0.f}, se1 = {0.f, 0.f, 0.f, 0.f};

        // software pipeline: idx regs hold pair p+1; data regs hold pair p
        int eA, sA, vA, eB, sB, vB;
        load_idx(csr, edge_src, start, end, start, eA, sA, vA);
        load_idx(csr, edge_src, start + 1, end, start, eB, sB, vB);
        uint2 kvA, kvB;
        float4 aA0, aA1, aB0, aB1;
        load_data(qkv, edge_attr, eA, sA, lane, kvA, aA0, aA1);
        load_data(qkv, edge_attr, eB, sB, lane, kvB, aB0, aB1);
        int vAc = vA, vBc = vB;
        load_idx(csr, edge_src, start + 2, end, start, eA, sA, vA);
        load_idx(csr, edge_src, start + 3, end, start, eB, sB, vB);

        for (int i = start + 2;; i += 2) {
            bool more = i < end;
            uint2 kvA2, kvB2;
            float4 aA02, aA12, aB02, aB12;
            int vA2 = vA, vB2 = vB;
            if (more) {
                load_data(qkv, edge_attr, eA, sA, lane, kvA2, aA02, aA12);
                load_data(qkv, edge_attr, eB, sB, lane, kvB2, aB02, aB12);
                load_idx(csr, edge_src, i + 2, end, start, eA, sA, vA);
                load_idx(csr, edge_src, i + 3, end, start, eB, sB, vB);
            }
            // process pair p (two independent shuffle chains)
            {
                float kxA = bfu(kvA.x & 0xffffu), kyA = bfu(kvA.x >> 16);
                float kxB = bfu(kvB.x & 0xffffu), kyB = bfu(kvB.x >> 16);
                float s0 = qx * kxA + qy * kyA;
                float s1 = qx * kxB + qy * kyB;
                s0 += __shfl_xor(s0, 1);  s1 += __shfl_xor(s1, 1);
                s0 += __shfl_xor(s0, 2);  s1 += __shfl_xor(s1, 2);
                s0 += __shfl_xor(s0, 4);  s1 += __shfl_xor(s1, 4);
                s0 += __shfl_xor(s0, 8);  s1 += __shfl_xor(s1, 8);
                s0 += __shfl_xor(s0, 16); s1 += __shfl_xor(s1, 16);
                s0 = s0 * 0.125f + qcA.x * aA0.x + qcA.y * aA0.y + qcA.z * aA0.z + qcA.w * aA0.w
                   + qcB.x * aA1.x + qcB.y * aA1.y + qcB.z * aA1.z + qcB.w * aA1.w + qb;
                s1 = s1 * 0.125f + qcA.x * aB0.x + qcA.y * aB0.y + qcA.z * aB0.z + qcA.w * aB0.w
                   + qcB.x * aB1.x + qcB.y * aB1.y + qcB.z * aB1.z + qcB.w * aB1.w + qb;
                float p0 = vAc ? __expf(fmaxf(s0, -60.f)) : 0.f;
                float p1 = vBc ? __expf(fmaxf(s1, -60.f)) : 0.f;
                lsum += p0 + p1;
                ax += p0 * bfu(kvA.y & 0xffffu) + p1 * bfu(kvB.y & 0xffffu);
                ay += p0 * bfu(kvA.y >> 16) + p1 * bfu(kvB.y >> 16);
                se0.x += p0 * aA0.x + p1 * aB0.x;
                se0.y += p0 * aA0.y + p1 * aB0.y;
                se0.z += p0 * aA0.z + p1 * aB0.z;
                se0.w += p0 * aA0.w + p1 * aB0.w;
                se1.x += p0 * aA1.x + p1 * aB1.x;
                se1.y += p0 * aA1.y + p1 * aB1.y;
                se1.z += p0 * aA1.z + p1 * aB1.z;
                se1.w += p0 * aA1.w + p1 * aB1.w;
            }
            if (!more) break;
            kvA = kvA2; aA0 = aA02; aA1 = aA12; vAc = vA2;
            kvB = kvB2; aB0 = aB02; aB1 = aB12; vBc = vB2;
        }

        int j0 = half * 64 + 2 * l31;
        float w0 = lsum * bc_s[j0], w1 = lsum * bc_s[j0 + 1];
        w0 += se0.x * Wc_s[0 * 128 + j0] + se0.y * Wc_s[1 * 128 + j0] +
              se0.z * Wc_s[2 * 128 + j0] + se0.w * Wc_s[3 * 128 + j0] +
              se1.x * Wc_s[4 * 128 + j0] + se1.y * Wc_s[5 * 128 + j0] +
              se1.z * Wc_s[6 * 128 + j0] + se1.w * Wc_s[7 * 128 + j0];
        w1 += se0.x * Wc_s[0 * 128 + j0 + 1] + se0.y * Wc_s[1 * 128 + j0 + 1] +
              se0.z * Wc_s[2 * 128 + j0 + 1] + se0.w * Wc_s[3 * 128 + j0 + 1] +
              se1.x * Wc_s[4 * 128 + j0 + 1] + se1.y * Wc_s[5 * 128 + j0 + 1] +
              se1.z * Wc_s[6 * 128 + j0 + 1] + se1.w * Wc_s[7 * 128 + j0 + 1];
        float inv = 1.f / lsum;
        float ox = (ax + w0) * inv, oy = (ay + w1) * inv;
        float px = __shfl_xor(ox, 32), py = __shfl_xor(oy, 32);
        ox = 0.5f * (ox + px);
        oy = 0.5f * (oy + py);
        if (half == 0) {
            float2* op = (float2*)(outbuf + (size_t)n * 64 + 2 * l31);
            float2 cur = *op;
            *op = make_float2(cur.x + ox, cur.y + oy);
        }
    }
}

// ---------------- BN: partial stats (grid must be 256) -> finalize -> apply ----

__global__ __launch_bounds__(256) void bnstats_kernel(const float* __restrict__ outbuf,
                                                      float* __restrict__ part, int N) {
    __shared__ float ssum[64], ssq[64];
    int t = threadIdx.x;
    if (t < 64) { ssum[t] = 0.f; ssq[t] = 0.f; }
    __syncthreads();
    float a = 0.f, b = 0.f;
    int idx0 = blockIdx.x * 256 + t;
    for (int idx = idx0; idx < N * 64; idx += 65536) {
        float v = outbuf[idx];
        a += v;
        b += v * v;
    }
    int c = t & 63;
    atomicAdd(&ssum[c], a);
    atomicAdd(&ssq[c], b);
    __syncthreads();
    if (t < 64) {
        part[blockIdx.x * 128 + t] = ssum[t];
        part[blockIdx.x * 128 + 64 + t] = ssq[t];
    }
}

__global__ void bnfinal_kernel(const float* __restrict__ part, float* __restrict__ bnbuf,
                               const float* __restrict__ gamma, const float* __restrict__ beta,
                               int N) {
    __shared__ float sums[128];
    int t = threadIdx.x;  // 128 threads
    float s = 0.f;
    for (int b = 0; b < 256; ++b) s += part[b * 128 + t];
    sums[t] = s;
    __syncthreads();
    if (t < 64) {
        float invN = 1.f / (float)N;
        float mean = sums[t] * invN;
        float var = sums[64 + t] * invN - mean * mean;
        float inv = rsqrtf(var + 1e-5f);
        float scale = gamma[t] * inv;
        bnbuf[t] = scale;
        bnbuf[64 + t] = beta[t] - mean * scale;
    }
}

__global__ __launch_bounds__(256) void bnapply_kernel(
    const float* __restrict__ outbuf, const float* __restrict__ bnbuf,
    const float* __restrict__ gate_W, const float* __restrict__ gate_b,
    const int* __restrict__ batch, float* __restrict__ h, ushort_t* __restrict__ h_bf,
    float* __restrict__ gatebuf, unsigned* __restrict__ gmax, int do_pool, int N) {
    int idx = blockIdx.x * 256 + threadIdx.x;
    if (idx >= N * 64) return;
    int c = idx & 63, n = idx >> 6;
    float o = outbuf[idx] * bnbuf[c] + bnbuf[64 + c];
    o = (o > 0.f) ? o : 0.01f * o;
    float hn = h[idx] + o;
    h[idx] = hn;
    h_bf[idx] = f2bf(hn);
    if (do_pool) {
        float g = hn * gate_W[c];
#pragma unroll
        for (int off = 32; off; off >>= 1) g += __shfl_xor(g, off);
        if (c == 0) {
            float gv = g + gate_b[0];
            gatebuf[n] = gv;
            atomicMax(&gmax[batch[n]], enc_f(gv));
        }
    }
}

// ---------------- pooling ----------------

__global__ __launch_bounds__(256) void pool_acc_kernel(
    const float* __restrict__ h, const float* __restrict__ gatebuf,
    const int* __restrict__ batch, const unsigned* __restrict__ gmax,
    float* __restrict__ pacc, float* __restrict__ pden, int N) {
    int b = blockIdx.x >> 3, chunk = blockIdx.x & 7;
    int lo = 0, hi = N;
    while (lo < hi) { int mid = (lo + hi) >> 1; if (batch[mid] < b) lo = mid + 1; else hi = mid; }
    int start = lo;
    lo = start; hi = N;
    while (lo < hi) { int mid = (lo + hi) >> 1; if (batch[mid] <= b) lo = mid + 1; else hi = mid; }
    int end = lo;
    int lane = threadIdx.x & 63, wid = threadIdx.x >> 6;
    int gwid = chunk * 4 + wid;
    float mb = dec_f(gmax[b]);
    float acc = 0.f, den = 0.f;
    for (int n = start + gwid; n < end; n += 32) {
        float ge = __expf(gatebuf[n] - mb);
        acc += ge * h[(size_t)n * 64 + lane];
        den += ge;
    }
    __shared__ float sacc[4][64];
    __shared__ float sden[4];
    sacc[wid][lane] = acc;
    if (lane == 0) sden[wid] = den;
    __syncthreads();
    if (wid == 0) {
        pacc[(size_t)blockIdx.x * 64 + lane] =
            sacc[0][lane] + sacc[1][lane] + sacc[2][lane] + sacc[3][lane];
        if (lane == 0) pden[blockIdx.x] = sden[0] + sden[1] + sden[2] + sden[3];
    }
}

__global__ void pool_fin_kernel(const float* __restrict__ pacc, const float* __restrict__ pden,
                                const float* __restrict__ out_W, const float* __restrict__ out_b,
                                float* __restrict__ out) {
    int b = blockIdx.x, c = threadIdx.x;
    float pc = 0.f, dv = 0.f;
#pragma unroll
    for (int j = 0; j < 8; ++j) {
        pc += pacc[(size_t)(b * 8 + j) * 64 + c];
        dv += pden[b * 8 + j];
    }
    float s = pc * out_W[c];
#pragma unroll
    for (int off = 32; off; off >>= 1) s += __shfl_xor(s, off);
    if (c == 0) {
        if (dv <= 0.f) dv = 1.f;
        float v = s / dv + out_b[0];
        out[b] = 1.f / (1.f + __expf(-v));
    }
}

// ---------------- host ----------------

extern "C" void kernel_launch(void* const* d_in, const int* in_sizes, int n_in,
                              void* d_out, int out_size, void* d_ws, size_t ws_size,
                              hipStream_t stream) {
    const float* x         = (const float*)d_in[0];
    const float* edge_attr = (const float*)d_in[1];
    const int*   edge_src  = (const int*)d_in[2];
    const int*   edge_dst  = (const int*)d_in[3];
    const int*   batch     = (const int*)d_in[4];
    const float* node_W    = (const float*)d_in[5];
    const float* node_b    = (const float*)d_in[6];
    const float* edge_W    = (const float*)d_in[7];
    const float* edge_b    = (const float*)d_in[8];
    const float* Wq        = (const float*)d_in[9];
    const float* bq        = (const float*)d_in[10];
    const float* Wk        = (const float*)d_in[11];
    const float* bk        = (const float*)d_in[12];
    const float* Wv        = (const float*)d_in[13];
    const float* bv        = (const float*)d_in[14];
    const float* We        = (const float*)d_in[15];
    const float* be        = (const float*)d_in[16];
    const float* Wskip     = (const float*)d_in[17];
    const float* bskip     = (const float*)d_in[18];
    const float* gamma     = (const float*)d_in[19];
    const float* beta      = (const float*)d_in[20];
    const float* gate_W    = (const float*)d_in[21];
    const float* gate_b    = (const float*)d_in[22];
    const float* out_W     = (const float*)d_in[23];
    const float* out_b     = (const float*)d_in[24];
    float* out = (float*)d_out;

    const int N = in_sizes[0] / 16;
    const int E = in_sizes[2];

    char* ws = (char*)d_ws;
    size_t off = 0;
    auto alloc = [&](size_t bytes) {
        size_t o = off;
        off += (bytes + 255) & ~(size_t)255;
        return o;
    };
    float*    h        = (float*)(ws + alloc((size_t)N * 64 * 4));
    ushort_t* h_bf     = (ushort_t*)(ws + alloc((size_t)N * 64 * 2));
    ushort_t* qkv      = (ushort_t*)(ws + alloc((size_t)N * 384 * 2));
    float*    outbuf   = (float*)(ws + alloc((size_t)N * 64 * 4));
    float*    qcbuf    = (float*)(ws + alloc((size_t)N * 20 * 4));
    int*      rowptr   = (int*)(ws + alloc((size_t)(N + 1) * 4));
    int*      cursor   = (int*)(ws + alloc((size_t)N * 4));
    int*      counts   = (int*)(ws + alloc((size_t)N * 4));
    int*      bsums    = (int*)(ws + alloc(1024));
    int*      csr      = (int*)(ws + alloc((size_t)E * 4));
    float*    Wc       = (float*)(ws + alloc(2 * 1024 * 4));
    float*    bcb      = (float*)(ws + alloc(2 * 128 * 4));
    float*    Wqc      = (float*)(ws + alloc(2 * 1152 * 4));
    float*    bias18   = (float*)(ws + alloc(2 * 18 * 4));
    ushort_t* Wall_arr = (ushort_t*)(ws + alloc(2 * 28672 * 2));
    float*    Wall_b   = (float*)(ws + alloc(2 * 448 * 4));
    float*    bnbuf    = (float*)(ws + alloc(128 * 4));
    float*    gatebuf  = (float*)(ws + alloc((size_t)N * 4));
    unsigned* gmax     = (unsigned*)(ws + alloc(64 * 4));
    float*    pacc     = (float*)(ws + alloc(512 * 64 * 4));
    float*    pden     = (float*)(ws + alloc(512 * 4));
    if (off > ws_size) return;

    // fused setup
    int O0 = (N * 64 + 255) / 256;
    int O1 = O0 + (N + 255) / 256;
    int O2 = O1 + 1;
    int O3 = O2 + 9;
    int O4 = O3 + 10;
    int O5 = O4 + 228;
    setup_kernel<<<O5, 256, 0, stream>>>(
        x, node_W, node_b, edge_W, edge_b, We, be, Wq, bq, Wk, bk, Wv, bv, Wskip, bskip,
        h, h_bf, counts, gmax, Wc, bcb, Wqc, bias18, Wall_arr, Wall_b,
        O0, O1, O2, O3, O4, N);

    csr_count_kernel<<<(E + 255) / 256, 256, 0, stream>>>(edge_dst, counts, E);
    int nb = (N + 255) / 256;
    scan1_kernel<<<nb, 256, 0, stream>>>(counts, rowptr, bsums, N);
    scan2_kernel<<<1, 256, 0, stream>>>(bsums, nb);
    scan3_kernel<<<nb, 256, 0, stream>>>(rowptr, bsums, cursor, N, E);
    csr_fill_kernel<<<(E + 255) / 256, 256, 0, stream>>>(edge_dst, cursor, csr, E);

    for (int l = 0; l < 2; ++l) {
        qkvqc_kernel<<<dim3((N + 15) / 16, 2), 256, 0, stream>>>(
            h, h_bf, Wall_arr + (size_t)l * 28672, Wall_b + l * 448,
            Wqc + l * 1152, bias18 + l * 18, qkv, outbuf, qcbuf, N);
        attn_kernel<<<(N + 3) / 4, 256, 0, stream>>>(qkv, qcbuf, edge_attr, edge_src,
                                                     rowptr, csr, Wc + l * 1024,
                                                     bcb + l * 128, outbuf, N);
        bnstats_kernel<<<256, 256, 0, stream>>>(outbuf, pacc, N);
        bnfinal_kernel<<<1, 128, 0, stream>>>(pacc, bnbuf, gamma + l * 64, beta + l * 64, N);
        bnapply_kernel<<<(N * 64 + 255) / 256, 256, 0, stream>>>(
            outbuf, bnbuf, gate_W, gate_b, batch, h, h_bf, gatebuf, gmax, (l == 1) ? 1 : 0, N);
    }

    pool_acc_kernel<<<512, 256, 0, stream>>>(h, gatebuf, batch, gmax, pacc, pden, N);
    pool_fin_kernel<<<64, 64, 0, stream>>>(pacc, pden, out_W, out_b, out);
}

// Round 8
// 868.605 us; speedup vs baseline: 1.4660x; 1.4660x over previous
//
#include <hip/hip_runtime.h>
#include <hip/hip_bf16.h>

typedef unsigned short ushort_t;
typedef __attribute__((ext_vector_type(8))) short short8;
typedef __attribute__((ext_vector_type(4))) float float4v;

__device__ __forceinline__ float bfu(ushort_t u) {
    return __uint_as_float(((unsigned)u) << 16);
}
__device__ __forceinline__ float bfu(unsigned u) {
    return __uint_as_float(u << 16);
}
__device__ __forceinline__ ushort_t f2bf(float f) {
    __hip_bfloat16 h = __float2bfloat16(f);
    return *reinterpret_cast<ushort_t*>(&h);
}
__device__ __forceinline__ unsigned enc_f(float f) {
    unsigned b = __float_as_uint(f);
    return (b & 0x80000000u) ? ~b : (b | 0x80000000u);
}
__device__ __forceinline__ float dec_f(unsigned b) {
    return (b & 0x80000000u) ? __uint_as_float(b & 0x7FFFFFFFu) : __uint_as_float(~b);
}

// ---------------- fused setup: node_enc + zeroing + combine_w + prep_w ----------------

__global__ __launch_bounds__(256) void setup_kernel(
    const float* __restrict__ x, const float* __restrict__ node_W,
    const float* __restrict__ node_b,
    const float* __restrict__ edge_W, const float* __restrict__ edge_b,
    const float* __restrict__ We, const float* __restrict__ be,
    const float* __restrict__ Wq, const float* __restrict__ bq,
    const float* __restrict__ Wk, const float* __restrict__ bk,
    const float* __restrict__ Wv, const float* __restrict__ bv,
    const float* __restrict__ Wskip, const float* __restrict__ bskip,
    float* __restrict__ h, ushort_t* __restrict__ h_bf,
    int* __restrict__ counts, unsigned* __restrict__ gmax,
    float* __restrict__ Wc, float* __restrict__ bcb,
    ushort_t* __restrict__ Wall_arr, float* __restrict__ Wall_bias,
    int O0, int O1, int O2, int O3, int N) {
    int b = blockIdx.x, t = threadIdx.x;
    if (b < O0) {
        int idx = b * 256 + t;
        if (idx < N * 64) {
            int n = idx >> 6, c = idx & 63;
            float acc = node_b[c];
#pragma unroll
            for (int j = 0; j < 16; ++j) acc += x[n * 16 + j] * node_W[j * 64 + c];
            h[idx] = acc;
            h_bf[idx] = f2bf(acc);
        }
    } else if (b < O1) {
        int i = (b - O0) * 256 + t;
        if (i < N) counts[i] = 0;
    } else if (b < O2) {
        if (t < 64) gmax[t] = 0u;
    } else if (b < O3) {
        int tid = (b - O2) * 256 + t;
        if (tid < 2048) {
            int l = tid >> 10, d = (tid >> 7) & 7, j = tid & 127;
            float s = 0.f;
            for (int m = 0; m < 64; ++m) s += edge_W[d * 64 + m] * We[l * 8192 + m * 128 + j];
            Wc[l * 1024 + d * 128 + j] = s;
        } else if (tid < 2048 + 256) {
            int u = tid - 2048;
            int l = u >> 7, j = u & 127;
            float s = be[l * 128 + j];
            for (int m = 0; m < 64; ++m) s += edge_b[m] * We[l * 8192 + m * 128 + j];
            bcb[l * 128 + j] = s;
        }
    } else {
        int tid = (b - O3) * 256 + t;
        if (tid < 2 * 28672) {
            int l = tid / 28672, u = tid % 28672;
            int j = u & 7, ln = (u >> 3) & 63, kch = (u >> 9) & 1, ct = u >> 10;
            int nn = ln & 15, quad = ln >> 4;
            int k = kch * 32 + quad * 8 + j;
            int col = ct * 16 + nn;
            float v;
            if (col < 128)      v = Wq[l * 8192 + k * 128 + col];
            else if (col < 256) v = Wk[l * 8192 + k * 128 + col - 128];
            else if (col < 384) v = Wv[l * 8192 + k * 128 + col - 256];
            else                v = Wskip[l * 4096 + k * 64 + col - 384];
            Wall_arr[(size_t)l * 28672 + u] = f2bf(v);
        } else if (tid < 2 * 28672 + 2 * 448) {
            int u = tid - 2 * 28672;
            int l = u / 448, col = u % 448;
            float v;
            if (col < 128)      v = bq[l * 128 + col];
            else if (col < 256) v = bk[l * 128 + col - 128];
            else if (col < 384) v = bv[l * 128 + col - 256];
            else                v = bskip[l * 64 + col - 384];
            Wall_bias[l * 448 + col] = v;
        }
    }
}

// combine2: Wqc_all[l][k][j] from precomputed Wc/bcb (cheap 64-iter loops)
__global__ void combine2_kernel(const float* __restrict__ Wq, const float* __restrict__ bq,
                                const float* __restrict__ Wc, const float* __restrict__ bcb,
                                float* __restrict__ Wqc_all, float* __restrict__ bias18) {
    int tid = blockIdx.x * 256 + threadIdx.x;
    if (tid < 2304) {
        int l = tid / 1152, u = tid % 1152, k = u / 18, j = u % 18;
        float s = 0.f;
        if (j < 16) {
            int hh = j >> 3, d = j & 7;
            for (int c = 0; c < 64; ++c)
                s += Wq[l * 8192 + k * 128 + hh * 64 + c] * Wc[l * 1024 + d * 128 + hh * 64 + c];
        } else {
            int hh = j - 16;
            for (int c = 0; c < 64; ++c)
                s += Wq[l * 8192 + k * 128 + hh * 64 + c] * bcb[l * 128 + hh * 64 + c];
        }
        Wqc_all[l * 1152 + k * 18 + j] = 0.125f * s;
    } else if (tid < 2304 + 36) {
        int u = tid - 2304;
        int l = u / 18, j = u % 18;
        float s = 0.f;
        if (j < 16) {
            int hh = j >> 3, d = j & 7;
            for (int c = 0; c < 64; ++c)
                s += bq[l * 128 + hh * 64 + c] * Wc[l * 1024 + d * 128 + hh * 64 + c];
        } else {
            int hh = j - 16;
            for (int c = 0; c < 64; ++c)
                s += bq[l * 128 + hh * 64 + c] * bcb[l * 128 + hh * 64 + c];
        }
        bias18[l * 18 + j] = 0.125f * s;
    }
}

// ---------------- CSR build (by dst) with src + edge_attr permutation ----------------

__global__ void csr_count_kernel(const int* __restrict__ dst, int* __restrict__ counts, int E) {
    int e = blockIdx.x * 256 + threadIdx.x;
    if (e < E) atomicAdd(&counts[dst[e]], 1);
}

__global__ void scan1_kernel(const int* __restrict__ counts, int* __restrict__ rowptr,
                             int* __restrict__ bsums, int N) {
    __shared__ int s[256];
    int t = threadIdx.x, i = blockIdx.x * 256 + t;
    int v = (i < N) ? counts[i] : 0;
    s[t] = v;
    __syncthreads();
    for (int d = 1; d < 256; d <<= 1) {
        int x = (t >= d) ? s[t - d] : 0;
        __syncthreads();
        s[t] += x;
        __syncthreads();
    }
    if (i < N) rowptr[i] = s[t] - v;
    if (t == 255) bsums[blockIdx.x] = s[255];
}

__global__ void scan2_kernel(int* __restrict__ bsums, int nb) {
    __shared__ int s[256];
    int t = threadIdx.x;
    int v = (t < nb) ? bsums[t] : 0;
    s[t] = v;
    __syncthreads();
    for (int d = 1; d < 256; d <<= 1) {
        int x = (t >= d) ? s[t - d] : 0;
        __syncthreads();
        s[t] += x;
        __syncthreads();
    }
    if (t < nb) bsums[t] = s[t] - v;
}

__global__ void scan3_kernel(int* __restrict__ rowptr, const int* __restrict__ bsums,
                             int* __restrict__ cursor, int N, int E) {
    int i = blockIdx.x * 256 + threadIdx.x;
    if (i < N) {
        int r = rowptr[i] + bsums[i >> 8];
        rowptr[i] = r;
        cursor[i] = r;
    }
    if (i == 0) rowptr[N] = E;
}

// fill: also pre-gather src and permute edge_attr into CSR order
__global__ void csr_fill_kernel(const int* __restrict__ dst, const int* __restrict__ src,
                                const float* __restrict__ edge_attr, int* __restrict__ cursor,
                                int* __restrict__ csr_src, float* __restrict__ ea_perm, int E) {
    int e = blockIdx.x * 256 + threadIdx.x;
    if (e < E) {
        int pos = atomicAdd(&cursor[dst[e]], 1);
        csr_src[pos] = src[e];
        float4 a0 = *(const float4*)(edge_attr + (size_t)e * 8);
        float4 a1 = *(const float4*)(edge_attr + (size_t)e * 8 + 4);
        *(float4*)(ea_perm + (size_t)pos * 8) = a0;
        *(float4*)(ea_perm + (size_t)pos * 8 + 4) = a1;
    }
}

// ---------------- per-layer: fused qkv-MFMA (y=0) + qc (y=1) ----------------
// qkv row layout (ushort units): q[0..127], then k/v interleaved in pairs:
//   k channel c -> 128 + 4*(c>>1) + (c&1);  v channel c -> 128 + 4*(c>>1) + 2 + (c&1)

__global__ __launch_bounds__(256) void qkvqc_kernel(
    const float* __restrict__ h, const ushort_t* __restrict__ h_bf,
    const ushort_t* __restrict__ Wall_arr, const float* __restrict__ Wall_bias,
    const float* __restrict__ Wqc, const float* __restrict__ bias18,
    ushort_t* __restrict__ qkv, float* __restrict__ outbuf, float* __restrict__ qcbuf, int N) {
    if (blockIdx.y == 0) {
        int wave = threadIdx.x >> 6, lane = threadIdx.x & 63;
        int quad = lane >> 4, nn = lane & 15;
        int n0 = blockIdx.x * 16;
        int node_a = n0 + nn;
        if (node_a >= N) node_a = N - 1;
        const ushort_t* ap = h_bf + (size_t)node_a * 64 + quad * 8;
        short8 a0 = *(const short8*)ap;
        short8 a1 = *(const short8*)(ap + 32);
#pragma unroll
        for (int i = 0; i < 7; ++i) {
            int ct = wave * 7 + i;
            const ushort_t* bp = Wall_arr + ((size_t)(ct * 2) * 64 + lane) * 8;
            short8 b0 = *(const short8*)bp;
            short8 b1 = *(const short8*)(bp + 512);
            float4v c = {0.f, 0.f, 0.f, 0.f};
            c = __builtin_amdgcn_mfma_f32_16x16x32_bf16(a0, b0, c, 0, 0, 0);
            c = __builtin_amdgcn_mfma_f32_16x16x32_bf16(a1, b1, c, 0, 0, 0);
            int col = ct * 16 + nn;
            float bias = Wall_bias[col];
            if (col < 384) {
                int cm;
                if (col < 128) cm = col;
                else if (col < 256) { int cc = col - 128; cm = 128 + ((cc >> 1) << 2) + (cc & 1); }
                else { int cc = col - 256; cm = 128 + ((cc >> 1) << 2) + 2 + (cc & 1); }
                ushort_t* qp = qkv + (size_t)(n0 + quad * 4) * 384 + cm;
#pragma unroll
                for (int r = 0; r < 4; ++r)
                    if (n0 + quad * 4 + r < N) qp[(size_t)r * 384] = f2bf(c[r] + bias);
            } else {
                float* op = outbuf + (size_t)(n0 + quad * 4) * 64 + (col - 384);
#pragma unroll
                for (int r = 0; r < 4; ++r)
                    if (n0 + quad * 4 + r < N) op[(size_t)r * 64] = c[r] + bias;
            }
        }
    } else {
        __shared__ float hs[16 * 64];
        __shared__ float w_s[64 * 18];
        __shared__ float b_s[18];
        int t = threadIdx.x;
        int n0 = blockIdx.x * 16;
        for (int i = t; i < 1152; i += 256) w_s[i] = Wqc[i];
        if (t < 18) b_s[t] = bias18[t];
        for (int i = t; i < 1024; i += 256) {
            int n = n0 + (i >> 6);
            hs[i] = (n < N) ? h[(size_t)n * 64 + (i & 63)] : 0.f;
        }
        __syncthreads();
        for (int o = t; o < 16 * 18; o += 256) {
            int nl = o / 18, j = o % 18;
            int n = n0 + nl;
            if (n < N) {
                float s = b_s[j];
                for (int k = 0; k < 64; ++k) s += hs[nl * 64 + k] * w_s[k * 18 + j];
                qcbuf[(size_t)n * 20 + j] = s;
            }
        }
    }
}

// ---------------- attention: one wave per node; segment-wide src preload,
// 4-edge chunks with next-chunk kv prefetch, interleaved shuffle chains ----

__global__ __launch_bounds__(256) void attn_kernel(
    const ushort_t* __restrict__ qkv, const float* __restrict__ qcbuf,
    const int* __restrict__ csr_src, const float* __restrict__ ea_perm,
    const int* __restrict__ rowptr,
    const float* __restrict__ Wc, const float* __restrict__ bcb,
    float* __restrict__ outbuf, int N) {
    __shared__ float Wc_s[1024];
    __shared__ float bc_s[128];
    int t = threadIdx.x;
    for (int i = t; i < 1024; i += 256) Wc_s[i] = Wc[i];
    if (t < 128) bc_s[t] = bcb[t];
    __syncthreads();
    int lane = t & 63, wid = t >> 6;
    int half = lane >> 5, l31 = lane & 31;
    for (int n = blockIdx.x * 4 + wid; n < N; n += gridDim.x * 4) {
        int start = rowptr[n], end = rowptr[n + 1];
        if (end <= start) continue;  // outbuf already holds skip
        unsigned qraw = *(const unsigned*)(qkv + (size_t)n * 384 + 2 * lane);
        float qx = bfu(qraw & 0xffffu), qy = bfu(qraw >> 16);
        const float4 qcA = *(const float4*)(qcbuf + (size_t)n * 20 + half * 8);
        const float4 qcB = *(const float4*)(qcbuf + (size_t)n * 20 + half * 8 + 4);
        float qb = qcbuf[(size_t)n * 20 + 16 + half];
        float lsum = 0.f, ax = 0.f, ay = 0.f;
        float4 se0 = {0.f, 0.f, 0.f, 0.f}, se1 = {0.f, 0.f, 0.f, 0.f};
        for (int seg = start; seg < end; seg += 64) {
            int segcnt = min(64, end - seg);
            int li = (lane < segcnt) ? lane : (segcnt - 1);
            int srcL = csr_src[seg + li];     // whole segment's srcs, one coalesced load
            uint2 kvc[4], kvn[4];
#pragma unroll
            for (int j = 0; j < 4; ++j) {
                int idx = (j < segcnt) ? j : (segcnt - 1);
                int s = __shfl(srcL, idx);
                kvc[j] = *(const uint2*)(qkv + (size_t)s * 384 + 128 + 4 * lane);
            }
            for (int base = 0; base < segcnt; base += 4) {
                int nb2 = base + 4;
                if (nb2 < segcnt) {
#pragma unroll
                    for (int j = 0; j < 4; ++j) {
                        int idx = (nb2 + j < segcnt) ? (nb2 + j) : (segcnt - 1);
                        int s = __shfl(srcL, idx);
                        kvn[j] = *(const uint2*)(qkv + (size_t)s * 384 + 128 + 4 * lane);
                    }
                }
                // broadcast ea loads (sequential region -> cache-hot)
                float4 a0[4], a1[4];
                float dt[4];
#pragma unroll
                for (int j = 0; j < 4; ++j) {
                    int gi = seg + base + ((base + j < segcnt) ? j : 0);
                    const float* eap = ea_perm + (size_t)gi * 8;
                    a0[j] = *(const float4*)eap;
                    a1[j] = *(const float4*)(eap + 4);
                    float kx = bfu(kvc[j].x & 0xffffu), ky = bfu(kvc[j].x >> 16);
                    dt[j] = qx * kx + qy * ky;
                }
#pragma unroll
                for (int m = 1; m <= 16; m <<= 1) {
#pragma unroll
                    for (int j = 0; j < 4; ++j) dt[j] += __shfl_xor(dt[j], m);
                }
#pragma unroll
                for (int j = 0; j < 4; ++j) {
                    float s0 = dt[j] * 0.125f
                        + qcA.x * a0[j].x + qcA.y * a0[j].y + qcA.z * a0[j].z + qcA.w * a0[j].w
                        + qcB.x * a1[j].x + qcB.y * a1[j].y + qcB.z * a1[j].z + qcB.w * a1[j].w
                        + qb;
                    float p = (base + j < segcnt) ? __expf(fmaxf(s0, -60.f)) : 0.f;
                    lsum += p;
                    ax += p * bfu(kvc[j].y & 0xffffu);
                    ay += p * bfu(kvc[j].y >> 16);
                    se0.x += p * a0[j].x; se0.y += p * a0[j].y;
                    se0.z += p * a0[j].z; se0.w += p * a0[j].w;
                    se1.x += p * a1[j].x; se1.y += p * a1[j].y;
                    se1.z += p * a1[j].z; se1.w += p * a1[j].w;
                }
#pragma unroll
                for (int j = 0; j < 4; ++j) kvc[j] = kvn[j];
            }
        }
        int j0 = half * 64 + 2 * l31;
        float w0 = lsum * bc_s[j0], w1 = lsum * bc_s[j0 + 1];
        w0 += se0.x * Wc_s[0 * 128 + j0] + se0.y * Wc_s[1 * 128 + j0] +
              se0.z * Wc_s[2 * 128 + j0] + se0.w * Wc_s[3 * 128 + j0] +
              se1.x * Wc_s[4 * 128 + j0] + se1.y * Wc_s[5 * 128 + j0] +
              se1.z * Wc_s[6 * 128 + j0] + se1.w * Wc_s[7 * 128 + j0];
        w1 += se0.x * Wc_s[0 * 128 + j0 + 1] + se0.y * Wc_s[1 * 128 + j0 + 1] +
              se0.z * Wc_s[2 * 128 + j0 + 1] + se0.w * Wc_s[3 * 128 + j0 + 1] +
              se1.x * Wc_s[4 * 128 + j0 + 1] + se1.y * Wc_s[5 * 128 + j0 + 1] +
              se1.z * Wc_s[6 * 128 + j0 + 1] + se1.w * Wc_s[7 * 128 + j0 + 1];
        float inv = 1.f / lsum;
        float ox = (ax + w0) * inv, oy = (ay + w1) * inv;
        float px = __shfl_xor(ox, 32), py = __shfl_xor(oy, 32);
        ox = 0.5f * (ox + px);
        oy = 0.5f * (oy + py);
        if (half == 0) {
            float2* op = (float2*)(outbuf + (size_t)n * 64 + 2 * l31);
            float2 cur = *op;
            *op = make_float2(cur.x + ox, cur.y + oy);
        }
    }
}

// ---------------- BN: partial stats (grid 256) -> finalize -> apply ----------------

__global__ __launch_bounds__(256) void bnstats_kernel(const float* __restrict__ outbuf,
                                                      float* __restrict__ part, int N) {
    __shared__ float ssum[64], ssq[64];
    int t = threadIdx.x;
    if (t < 64) { ssum[t] = 0.f; ssq[t] = 0.f; }
    __syncthreads();
    float a = 0.f, b = 0.f;
    int idx0 = blockIdx.x * 256 + t;
    for (int idx = idx0; idx < N * 64; idx += 65536) {
        float v = outbuf[idx];
        a += v;
        b += v * v;
    }
    int c = t & 63;
    atomicAdd(&ssum[c], a);
    atomicAdd(&ssq[c], b);
    __syncthreads();
    if (t < 64) {
        part[blockIdx.x * 128 + t] = ssum[t];
        part[blockIdx.x * 128 + 64 + t] = ssq[t];
    }
}

__global__ void bnfinal_kernel(const float* __restrict__ part, float* __restrict__ bnbuf,
                               const float* __restrict__ gamma, const float* __restrict__ beta,
                               int N) {
    __shared__ float sums[128];
    int t = threadIdx.x;  // 128 threads
    float s = 0.f;
    for (int b = 0; b < 256; ++b) s += part[b * 128 + t];
    sums[t] = s;
    __syncthreads();
    if (t < 64) {
        float invN = 1.f / (float)N;
        float mean = sums[t] * invN;
        float var = sums[64 + t] * invN - mean * mean;
        float inv = rsqrtf(var + 1e-5f);
        float scale = gamma[t] * inv;
        bnbuf[t] = scale;
        bnbuf[64 + t] = beta[t] - mean * scale;
    }
}

__global__ __launch_bounds__(256) void bnapply_kernel(
    const float* __restrict__ outbuf, const float* __restrict__ bnbuf,
    const float* __restrict__ gate_W, const float* __restrict__ gate_b,
    const int* __restrict__ batch, float* __restrict__ h, ushort_t* __restrict__ h_bf,
    float* __restrict__ gatebuf, unsigned* __restrict__ gmax, int do_pool, int N) {
    int idx = blockIdx.x * 256 + threadIdx.x;
    if (idx >= N * 64) return;
    int c = idx & 63, n = idx >> 6;
    float o = outbuf[idx] * bnbuf[c] + bnbuf[64 + c];
    o = (o > 0.f) ? o : 0.01f * o;
    float hn = h[idx] + o;
    h[idx] = hn;
    h_bf[idx] = f2bf(hn);
    if (do_pool) {
        float g = hn * gate_W[c];
#pragma unroll
        for (int off = 32; off; off >>= 1) g += __shfl_xor(g, off);
        if (c == 0) {
            float gv = g + gate_b[0];
            gatebuf[n] = gv;
            atomicMax(&gmax[batch[n]], enc_f(gv));
        }
    }
}

// ---------------- pooling ----------------

__global__ __launch_bounds__(256) void pool_acc_kernel(
    const float* __restrict__ h, const float* __restrict__ gatebuf,
    const int* __restrict__ batch, const unsigned* __restrict__ gmax,
    float* __restrict__ pacc, float* __restrict__ pden, int N) {
    int b = blockIdx.x >> 3, chunk = blockIdx.x & 7;
    int lo = 0, hi = N;
    while (lo < hi) { int mid = (lo + hi) >> 1; if (batch[mid] < b) lo = mid + 1; else hi = mid; }
    int start = lo;
    lo = start; hi = N;
    while (lo < hi) { int mid = (lo + hi) >> 1; if (batch[mid] <= b) lo = mid + 1; else hi = mid; }
    int end = lo;
    int lane = threadIdx.x & 63, wid = threadIdx.x >> 6;
    int gwid = chunk * 4 + wid;
    float mb = dec_f(gmax[b]);
    float acc = 0.f, den = 0.f;
    for (int n = start + gwid; n < end; n += 32) {
        float ge = __expf(gatebuf[n] - mb);
        acc += ge * h[(size_t)n * 64 + lane];
        den += ge;
    }
    __shared__ float sacc[4][64];
    __shared__ float sden[4];
    sacc[wid][lane] = acc;
    if (lane == 0) sden[wid] = den;
    __syncthreads();
    if (wid == 0) {
        pacc[(size_t)blockIdx.x * 64 + lane] =
            sacc[0][lane] + sacc[1][lane] + sacc[2][lane] + sacc[3][lane];
        if (lane == 0) pden[blockIdx.x] = sden[0] + sden[1] + sden[2] + sden[3];
    }
}

__global__ void pool_fin_kernel(const float* __restrict__ pacc, const float* __restrict__ pden,
                                const float* __restrict__ out_W, const float* __restrict__ out_b,
                                float* __restrict__ out) {
    int b = blockIdx.x, c = threadIdx.x;
    float pc = 0.f, dv = 0.f;
#pragma unroll
    for (int j = 0; j < 8; ++j) {
        pc += pacc[(size_t)(b * 8 + j) * 64 + c];
        dv += pden[b * 8 + j];
    }
    float s = pc * out_W[c];
#pragma unroll
    for (int off = 32; off; off >>= 1) s += __shfl_xor(s, off);
    if (c == 0) {
        if (dv <= 0.f) dv = 1.f;
        float v = s / dv + out_b[0];
        out[b] = 1.f / (1.f + __expf(-v));
    }
}

// ---------------- host ----------------

extern "C" void kernel_launch(void* const* d_in, const int* in_sizes, int n_in,
                              void* d_out, int out_size, void* d_ws, size_t ws_size,
                              hipStream_t stream) {
    const float* x         = (const float*)d_in[0];
    const float* edge_attr = (const float*)d_in[1];
    const int*   edge_src  = (const int*)d_in[2];
    const int*   edge_dst  = (const int*)d_in[3];
    const int*   batch     = (const int*)d_in[4];
    const float* node_W    = (const float*)d_in[5];
    const float* node_b    = (const float*)d_in[6];
    const float* edge_W    = (const float*)d_in[7];
    const float* edge_b    = (const float*)d_in[8];
    const float* Wq        = (const float*)d_in[9];
    const float* bq        = (const float*)d_in[10];
    const float* Wk        = (const float*)d_in[11];
    const float* bk        = (const float*)d_in[12];
    const float* Wv        = (const float*)d_in[13];
    const float* bv        = (const float*)d_in[14];
    const float* We        = (const float*)d_in[15];
    const float* be        = (const float*)d_in[16];
    const float* Wskip     = (const float*)d_in[17];
    const float* bskip     = (const float*)d_in[18];
    const float* gamma     = (const float*)d_in[19];
    const float* beta      = (const float*)d_in[20];
    const float* gate_W    = (const float*)d_in[21];
    const float* gate_b    = (const float*)d_in[22];
    const float* out_W     = (const float*)d_in[23];
    const float* out_b     = (const float*)d_in[24];
    float* out = (float*)d_out;

    const int N = in_sizes[0] / 16;
    const int E = in_sizes[2];

    char* ws = (char*)d_ws;
    size_t off = 0;
    auto alloc = [&](size_t bytes) {
        size_t o = off;
        off += (bytes + 255) & ~(size_t)255;
        return o;
    };
    float*    h        = (float*)(ws + alloc((size_t)N * 64 * 4));
    ushort_t* h_bf     = (ushort_t*)(ws + alloc((size_t)N * 64 * 2));
    ushort_t* qkv      = (ushort_t*)(ws + alloc((size_t)N * 384 * 2));
    float*    outbuf   = (float*)(ws + alloc((size_t)N * 64 * 4));
    float*    qcbuf    = (float*)(ws + alloc((size_t)N * 20 * 4));
    int*      rowptr   = (int*)(ws + alloc((size_t)(N + 1) * 4));
    int*      cursor   = (int*)(ws + alloc((size_t)N * 4));
    int*      counts   = (int*)(ws + alloc((size_t)N * 4));
    int*      bsums    = (int*)(ws + alloc(1024));
    int*      csr_src  = (int*)(ws + alloc((size_t)E * 4));
    float*    ea_perm  = (float*)(ws + alloc((size_t)E * 8 * 4));
    float*    Wc       = (float*)(ws + alloc(2 * 1024 * 4));
    float*    bcb      = (float*)(ws + alloc(2 * 128 * 4));
    float*    Wqc      = (float*)(ws + alloc(2 * 1152 * 4));
    float*    bias18   = (float*)(ws + alloc(2 * 18 * 4));
    ushort_t* Wall_arr = (ushort_t*)(ws + alloc(2 * 28672 * 2));
    float*    Wall_b   = (float*)(ws + alloc(2 * 448 * 4));
    float*    bnbuf    = (float*)(ws + alloc(128 * 4));
    float*    gatebuf  = (float*)(ws + alloc((size_t)N * 4));
    unsigned* gmax     = (unsigned*)(ws + alloc(64 * 4));
    float*    pacc     = (float*)(ws + alloc(512 * 64 * 4));
    float*    pden     = (float*)(ws + alloc(512 * 4));
    if (off > ws_size) return;

    int O0 = (N * 64 + 255) / 256;
    int O1 = O0 + (N + 255) / 256;
    int O2 = O1 + 1;
    int O3 = O2 + 9;
    int O4 = O3 + 228;
    setup_kernel<<<O4, 256, 0, stream>>>(
        x, node_W, node_b, edge_W, edge_b, We, be, Wq, bq, Wk, bk, Wv, bv, Wskip, bskip,
        h, h_bf, counts, gmax, Wc, bcb, Wall_arr, Wall_b, O0, O1, O2, O3, N);
    combine2_kernel<<<10, 256, 0, stream>>>(Wq, bq, Wc, bcb, Wqc, bias18);

    csr_count_kernel<<<(E + 255) / 256, 256, 0, stream>>>(edge_dst, counts, E);
    int nb = (N + 255) / 256;
    scan1_kernel<<<nb, 256, 0, stream>>>(counts, rowptr, bsums, N);
    scan2_kernel<<<1, 256, 0, stream>>>(bsums, nb);
    scan3_kernel<<<nb, 256, 0, stream>>>(rowptr, bsums, cursor, N, E);
    csr_fill_kernel<<<(E + 255) / 256, 256, 0, stream>>>(edge_dst, edge_src, edge_attr,
                                                         cursor, csr_src, ea_perm, E);

    for (int l = 0; l < 2; ++l) {
        qkvqc_kernel<<<dim3((N + 15) / 16, 2), 256, 0, stream>>>(
            h, h_bf, Wall_arr + (size_t)l * 28672, Wall_b + l * 448,
            Wqc + l * 1152, bias18 + l * 18, qkv, outbuf, qcbuf, N);
        attn_kernel<<<(N + 3) / 4, 256, 0, stream>>>(qkv, qcbuf, csr_src, ea_perm,
                                                     rowptr, Wc + l * 1024,
                                                     bcb + l * 128, outbuf, N);
        bnstats_kernel<<<256, 256, 0, stream>>>(outbuf, pacc, N);
        bnfinal_kernel<<<1, 128, 0, stream>>>(pacc, bnbuf, gamma + l * 64, beta + l * 64, N);
        bnapply_kernel<<<(N * 64 + 255) / 256, 256, 0, stream>>>(
            outbuf, bnbuf, gate_W, gate_b, batch, h, h_bf, gatebuf, gmax, (l == 1) ? 1 : 0, N);
    }

    pool_acc_kernel<<<512, 256, 0, stream>>>(h, gatebuf, batch, gmax, pacc, pden, N);
    pool_fin_kernel<<<64, 64, 0, stream>>>(pacc, pden, out_W, out_b, out);
}

// Round 9
// 532.336 us; speedup vs baseline: 2.3920x; 1.6317x over previous
//
#include <hip/hip_runtime.h>
#include <hip/hip_bf16.h>

typedef unsigned short ushort_t;
typedef __attribute__((ext_vector_type(8))) short short8;
typedef __attribute__((ext_vector_type(4))) float float4v;

__device__ __forceinline__ float bfu(ushort_t u) {
    return __uint_as_float(((unsigned)u) << 16);
}
__device__ __forceinline__ float bfu(unsigned u) {
    return __uint_as_float(u << 16);
}
__device__ __forceinline__ ushort_t f2bf(float f) {
    __hip_bfloat16 h = __float2bfloat16(f);
    return *reinterpret_cast<ushort_t*>(&h);
}

// ---------------- fused setup: node_enc + zeroing + combine_w + prep_w ----------------

__global__ __launch_bounds__(256) void setup_kernel(
    const float* __restrict__ x, const float* __restrict__ node_W,
    const float* __restrict__ node_b,
    const float* __restrict__ edge_W, const float* __restrict__ edge_b,
    const float* __restrict__ We, const float* __restrict__ be,
    const float* __restrict__ Wq, const float* __restrict__ bq,
    const float* __restrict__ Wk, const float* __restrict__ bk,
    const float* __restrict__ Wv, const float* __restrict__ bv,
    const float* __restrict__ Wskip, const float* __restrict__ bskip,
    float* __restrict__ h, ushort_t* __restrict__ h_bf,
    int* __restrict__ counts,
    float* __restrict__ Wc, float* __restrict__ bcb,
    ushort_t* __restrict__ Wall_arr, float* __restrict__ Wall_bias,
    int O0, int O1, int O2, int N) {
    int b = blockIdx.x, t = threadIdx.x;
    if (b < O0) {
        int idx = b * 256 + t;
        if (idx < N * 64) {
            int n = idx >> 6, c = idx & 63;
            float acc = node_b[c];
#pragma unroll
            for (int j = 0; j < 16; ++j) acc += x[n * 16 + j] * node_W[j * 64 + c];
            h[idx] = acc;
            h_bf[idx] = f2bf(acc);
        }
    } else if (b < O1) {
        int i = (b - O0) * 256 + t;
        if (i < N) counts[i] = 0;
    } else if (b < O2) {
        int tid = (b - O1) * 256 + t;
        if (tid < 2048) {
            int l = tid >> 10, d = (tid >> 7) & 7, j = tid & 127;
            float s = 0.f;
            for (int m = 0; m < 64; ++m) s += edge_W[d * 64 + m] * We[l * 8192 + m * 128 + j];
            Wc[l * 1024 + d * 128 + j] = s;
        } else if (tid < 2048 + 256) {
            int u = tid - 2048;
            int l = u >> 7, j = u & 127;
            float s = be[l * 128 + j];
            for (int m = 0; m < 64; ++m) s += edge_b[m] * We[l * 8192 + m * 128 + j];
            bcb[l * 128 + j] = s;
        }
    } else {
        int tid = (b - O2) * 256 + t;
        if (tid < 2 * 28672) {
            int l = tid / 28672, u = tid % 28672;
            int j = u & 7, ln = (u >> 3) & 63, kch = (u >> 9) & 1, ct = u >> 10;
            int nn = ln & 15, quad = ln >> 4;
            int k = kch * 32 + quad * 8 + j;
            int col = ct * 16 + nn;
            float v;
            if (col < 128)      v = Wq[l * 8192 + k * 128 + col];
            else if (col < 256) v = Wk[l * 8192 + k * 128 + col - 128];
            else if (col < 384) v = Wv[l * 8192 + k * 128 + col - 256];
            else                v = Wskip[l * 4096 + k * 64 + col - 384];
            Wall_arr[(size_t)l * 28672 + u] = f2bf(v);
        } else if (tid < 2 * 28672 + 2 * 448) {
            int u = tid - 2 * 28672;
            int l = u / 448, col = u % 448;
            float v;
            if (col < 128)      v = bq[l * 128 + col];
            else if (col < 256) v = bk[l * 128 + col - 128];
            else if (col < 384) v = bv[l * 128 + col - 256];
            else                v = bskip[l * 64 + col - 384];
            Wall_bias[l * 448 + col] = v;
        }
    }
}

// combine2: Wqc_all[l][k][j] from precomputed Wc/bcb (cheap 64-iter loops)
__global__ void combine2_kernel(const float* __restrict__ Wq, const float* __restrict__ bq,
                                const float* __restrict__ Wc, const float* __restrict__ bcb,
                                float* __restrict__ Wqc_all, float* __restrict__ bias18) {
    int tid = blockIdx.x * 256 + threadIdx.x;
    if (tid < 2304) {
        int l = tid / 1152, u = tid % 1152, k = u / 18, j = u % 18;
        float s = 0.f;
        if (j < 16) {
            int hh = j >> 3, d = j & 7;
            for (int c = 0; c < 64; ++c)
                s += Wq[l * 8192 + k * 128 + hh * 64 + c] * Wc[l * 1024 + d * 128 + hh * 64 + c];
        } else {
            int hh = j - 16;
            for (int c = 0; c < 64; ++c)
                s += Wq[l * 8192 + k * 128 + hh * 64 + c] * bcb[l * 128 + hh * 64 + c];
        }
        Wqc_all[l * 1152 + k * 18 + j] = 0.125f * s;
    } else if (tid < 2304 + 36) {
        int u = tid - 2304;
        int l = u / 18, j = u % 18;
        float s = 0.f;
        if (j < 16) {
            int hh = j >> 3, d = j & 7;
            for (int c = 0; c < 64; ++c)
                s += bq[l * 128 + hh * 64 + c] * Wc[l * 1024 + d * 128 + hh * 64 + c];
        } else {
            int hh = j - 16;
            for (int c = 0; c < 64; ++c)
                s += bq[l * 128 + hh * 64 + c] * bcb[l * 128 + hh * 64 + c];
        }
        bias18[l * 18 + j] = 0.125f * s;
    }
}

// ---------------- CSR build (by dst) with src + edge_attr permutation ----------------

__global__ void csr_count_kernel(const int* __restrict__ dst, int* __restrict__ counts, int E) {
    int e = blockIdx.x * 256 + threadIdx.x;
    if (e < E) atomicAdd(&counts[dst[e]], 1);
}

__global__ void scan1_kernel(const int* __restrict__ counts, int* __restrict__ rowptr,
                             int* __restrict__ bsums, int N) {
    __shared__ int s[256];
    int t = threadIdx.x, i = blockIdx.x * 256 + t;
    int v = (i < N) ? counts[i] : 0;
    s[t] = v;
    __syncthreads();
    for (int d = 1; d < 256; d <<= 1) {
        int x = (t >= d) ? s[t - d] : 0;
        __syncthreads();
        s[t] += x;
        __syncthreads();
    }
    if (i < N) rowptr[i] = s[t] - v;
    if (t == 255) bsums[blockIdx.x] = s[255];
}

__global__ void scan2_kernel(int* __restrict__ bsums, int nb) {
    __shared__ int s[256];
    int t = threadIdx.x;
    int v = (t < nb) ? bsums[t] : 0;
    s[t] = v;
    __syncthreads();
    for (int d = 1; d < 256; d <<= 1) {
        int x = (t >= d) ? s[t - d] : 0;
        __syncthreads();
        s[t] += x;
        __syncthreads();
    }
    if (t < nb) bsums[t] = s[t] - v;
}

__global__ void scan3_kernel(int* __restrict__ rowptr, const int* __restrict__ bsums,
                             int* __restrict__ cursor, int N, int E) {
    int i = blockIdx.x * 256 + threadIdx.x;
    if (i < N) {
        int r = rowptr[i] + bsums[i >> 8];
        rowptr[i] = r;
        cursor[i] = r;
    }
    if (i == 0) rowptr[N] = E;
}

// fill: also pre-gather src and permute edge_attr into CSR order
__global__ void csr_fill_kernel(const int* __restrict__ dst, const int* __restrict__ src,
                                const float* __restrict__ edge_attr, int* __restrict__ cursor,
                                int* __restrict__ csr_src, float* __restrict__ ea_perm, int E) {
    int e = blockIdx.x * 256 + threadIdx.x;
    if (e < E) {
        int pos = atomicAdd(&cursor[dst[e]], 1);
        csr_src[pos] = src[e];
        float4 a0 = *(const float4*)(edge_attr + (size_t)e * 8);
        float4 a1 = *(const float4*)(edge_attr + (size_t)e * 8 + 4);
        *(float4*)(ea_perm + (size_t)pos * 8) = a0;
        *(float4*)(ea_perm + (size_t)pos * 8 + 4) = a1;
    }
}

// ---------------- per-layer: fused qkv-MFMA (y=0) + qc (y=1) ----------------
// qkv row layout (ushort units): q[0..127], then k/v interleaved in pairs:
//   k channel c -> 128 + 4*(c>>1) + (c&1);  v channel c -> 128 + 4*(c>>1) + 2 + (c&1)

__global__ __launch_bounds__(256) void qkvqc_kernel(
    const float* __restrict__ h, const ushort_t* __restrict__ h_bf,
    const ushort_t* __restrict__ Wall_arr, const float* __restrict__ Wall_bias,
    const float* __restrict__ Wqc, const float* __restrict__ bias18,
    ushort_t* __restrict__ qkv, float* __restrict__ outbuf, float* __restrict__ qcbuf, int N) {
    if (blockIdx.y == 0) {
        int wave = threadIdx.x >> 6, lane = threadIdx.x & 63;
        int quad = lane >> 4, nn = lane & 15;
        int n0 = blockIdx.x * 16;
        int node_a = n0 + nn;
        if (node_a >= N) node_a = N - 1;
        const ushort_t* ap = h_bf + (size_t)node_a * 64 + quad * 8;
        short8 a0 = *(const short8*)ap;
        short8 a1 = *(const short8*)(ap + 32);
#pragma unroll
        for (int i = 0; i < 7; ++i) {
            int ct = wave * 7 + i;
            const ushort_t* bp = Wall_arr + ((size_t)(ct * 2) * 64 + lane) * 8;
            short8 b0 = *(const short8*)bp;
            short8 b1 = *(const short8*)(bp + 512);
            float4v c = {0.f, 0.f, 0.f, 0.f};
            c = __builtin_amdgcn_mfma_f32_16x16x32_bf16(a0, b0, c, 0, 0, 0);
            c = __builtin_amdgcn_mfma_f32_16x16x32_bf16(a1, b1, c, 0, 0, 0);
            int col = ct * 16 + nn;
            float bias = Wall_bias[col];
            if (col < 384) {
                int cm;
                if (col < 128) cm = col;
                else if (col < 256) { int cc = col - 128; cm = 128 + ((cc >> 1) << 2) + (cc & 1); }
                else { int cc = col - 256; cm = 128 + ((cc >> 1) << 2) + 2 + (cc & 1); }
                ushort_t* qp = qkv + (size_t)(n0 + quad * 4) * 384 + cm;
#pragma unroll
                for (int r = 0; r < 4; ++r)
                    if (n0 + quad * 4 + r < N) qp[(size_t)r * 384] = f2bf(c[r] + bias);
            } else {
                float* op = outbuf + (size_t)(n0 + quad * 4) * 64 + (col - 384);
#pragma unroll
                for (int r = 0; r < 4; ++r)
                    if (n0 + quad * 4 + r < N) op[(size_t)r * 64] = c[r] + bias;
            }
        }
    } else {
        __shared__ float hs[16 * 64];
        __shared__ float w_s[64 * 18];
        __shared__ float b_s[18];
        int t = threadIdx.x;
        int n0 = blockIdx.x * 16;
        for (int i = t; i < 1152; i += 256) w_s[i] = Wqc[i];
        if (t < 18) b_s[t] = bias18[t];
        for (int i = t; i < 1024; i += 256) {
            int n = n0 + (i >> 6);
            hs[i] = (n < N) ? h[(size_t)n * 64 + (i & 63)] : 0.f;
        }
        __syncthreads();
        for (int o = t; o < 16 * 18; o += 256) {
            int nl = o / 18, j = o % 18;
            int n = n0 + nl;
            if (n < N) {
                float s = b_s[j];
                for (int k = 0; k < 64; ++k) s += hs[nl * 64 + k] * w_s[k * 18 + j];
                qcbuf[(size_t)n * 20 + j] = s;
            }
        }
    }
}

// ---------------- attention: one wave per node; segment-wide src preload,
// 4-edge chunks with next-chunk kv prefetch, interleaved shuffle chains ----

__global__ __launch_bounds__(256) void attn_kernel(
    const ushort_t* __restrict__ qkv, const float* __restrict__ qcbuf,
    const int* __restrict__ csr_src, const float* __restrict__ ea_perm,
    const int* __restrict__ rowptr,
    const float* __restrict__ Wc, const float* __restrict__ bcb,
    float* __restrict__ outbuf, int N) {
    __shared__ float Wc_s[1024];
    __shared__ float bc_s[128];
    int t = threadIdx.x;
    for (int i = t; i < 1024; i += 256) Wc_s[i] = Wc[i];
    if (t < 128) bc_s[t] = bcb[t];
    __syncthreads();
    int lane = t & 63, wid = t >> 6;
    int half = lane >> 5, l31 = lane & 31;
    for (int n = blockIdx.x * 4 + wid; n < N; n += gridDim.x * 4) {
        int start = rowptr[n], end = rowptr[n + 1];
        if (end <= start) continue;  // outbuf already holds skip
        unsigned qraw = *(const unsigned*)(qkv + (size_t)n * 384 + 2 * lane);
        float qx = bfu(qraw & 0xffffu), qy = bfu(qraw >> 16);
        const float4 qcA = *(const float4*)(qcbuf + (size_t)n * 20 + half * 8);
        const float4 qcB = *(const float4*)(qcbuf + (size_t)n * 20 + half * 8 + 4);
        float qb = qcbuf[(size_t)n * 20 + 16 + half];
        float lsum = 0.f, ax = 0.f, ay = 0.f;
        float4 se0 = {0.f, 0.f, 0.f, 0.f}, se1 = {0.f, 0.f, 0.f, 0.f};
        for (int seg = start; seg < end; seg += 64) {
            int segcnt = min(64, end - seg);
            int li = (lane < segcnt) ? lane : (segcnt - 1);
            int srcL = csr_src[seg + li];     // whole segment's srcs, one coalesced load
            uint2 kvc[4], kvn[4];
#pragma unroll
            for (int j = 0; j < 4; ++j) {
                int idx = (j < segcnt) ? j : (segcnt - 1);
                int s = __shfl(srcL, idx);
                kvc[j] = *(const uint2*)(qkv + (size_t)s * 384 + 128 + 4 * lane);
            }
            for (int base = 0; base < segcnt; base += 4) {
                int nb2 = base + 4;
                if (nb2 < segcnt) {
#pragma unroll
                    for (int j = 0; j < 4; ++j) {
                        int idx = (nb2 + j < segcnt) ? (nb2 + j) : (segcnt - 1);
                        int s = __shfl(srcL, idx);
                        kvn[j] = *(const uint2*)(qkv + (size_t)s * 384 + 128 + 4 * lane);
                    }
                }
                float4 a0[4], a1[4];
                float dt[4];
#pragma unroll
                for (int j = 0; j < 4; ++j) {
                    int gi = seg + base + ((base + j < segcnt) ? j : 0);
                    const float* eap = ea_perm + (size_t)gi * 8;
                    a0[j] = *(const float4*)eap;
                    a1[j] = *(const float4*)(eap + 4);
                    float kx = bfu(kvc[j].x & 0xffffu), ky = bfu(kvc[j].x >> 16);
                    dt[j] = qx * kx + qy * ky;
                }
#pragma unroll
                for (int m = 1; m <= 16; m <<= 1) {
#pragma unroll
                    for (int j = 0; j < 4; ++j) dt[j] += __shfl_xor(dt[j], m);
                }
#pragma unroll
                for (int j = 0; j < 4; ++j) {
                    float s0 = dt[j] * 0.125f
                        + qcA.x * a0[j].x + qcA.y * a0[j].y + qcA.z * a0[j].z + qcA.w * a0[j].w
                        + qcB.x * a1[j].x + qcB.y * a1[j].y + qcB.z * a1[j].z + qcB.w * a1[j].w
                        + qb;
                    float p = (base + j < segcnt) ? __expf(fmaxf(s0, -60.f)) : 0.f;
                    lsum += p;
                    ax += p * bfu(kvc[j].y & 0xffffu);
                    ay += p * bfu(kvc[j].y >> 16);
                    se0.x += p * a0[j].x; se0.y += p * a0[j].y;
                    se0.z += p * a0[j].z; se0.w += p * a0[j].w;
                    se1.x += p * a1[j].x; se1.y += p * a1[j].y;
                    se1.z += p * a1[j].z; se1.w += p * a1[j].w;
                }
#pragma unroll
                for (int j = 0; j < 4; ++j) kvc[j] = kvn[j];
            }
        }
        int j0 = half * 64 + 2 * l31;
        float w0 = lsum * bc_s[j0], w1 = lsum * bc_s[j0 + 1];
        w0 += se0.x * Wc_s[0 * 128 + j0] + se0.y * Wc_s[1 * 128 + j0] +
              se0.z * Wc_s[2 * 128 + j0] + se0.w * Wc_s[3 * 128 + j0] +
              se1.x * Wc_s[4 * 128 + j0] + se1.y * Wc_s[5 * 128 + j0] +
              se1.z * Wc_s[6 * 128 + j0] + se1.w * Wc_s[7 * 128 + j0];
        w1 += se0.x * Wc_s[0 * 128 + j0 + 1] + se0.y * Wc_s[1 * 128 + j0 + 1] +
              se0.z * Wc_s[2 * 128 + j0 + 1] + se0.w * Wc_s[3 * 128 + j0 + 1] +
              se1.x * Wc_s[4 * 128 + j0 + 1] + se1.y * Wc_s[5 * 128 + j0 + 1] +
              se1.z * Wc_s[6 * 128 + j0 + 1] + se1.w * Wc_s[7 * 128 + j0 + 1];
        float inv = 1.f / lsum;
        float ox = (ax + w0) * inv, oy = (ay + w1) * inv;
        float px = __shfl_xor(ox, 32), py = __shfl_xor(oy, 32);
        ox = 0.5f * (ox + px);
        oy = 0.5f * (oy + py);
        if (half == 0) {
            float2* op = (float2*)(outbuf + (size_t)n * 64 + 2 * l31);
            float2 cur = *op;
            *op = make_float2(cur.x + ox, cur.y + oy);
        }
    }
}

// ---------------- BN: partial stats (grid 256) -> finalize -> apply ----------------

__global__ __launch_bounds__(256) void bnstats_kernel(const float* __restrict__ outbuf,
                                                      float* __restrict__ part, int N) {
    __shared__ float ssum[64], ssq[64];
    int t = threadIdx.x;
    if (t < 64) { ssum[t] = 0.f; ssq[t] = 0.f; }
    __syncthreads();
    float a = 0.f, b = 0.f;
    int idx0 = blockIdx.x * 256 + t;
    for (int idx = idx0; idx < N * 64; idx += 65536) {
        float v = outbuf[idx];
        a += v;
        b += v * v;
    }
    int c = t & 63;
    atomicAdd(&ssum[c], a);
    atomicAdd(&ssq[c], b);
    __syncthreads();
    if (t < 64) {
        part[blockIdx.x * 128 + t] = ssum[t];
        part[blockIdx.x * 128 + 64 + t] = ssq[t];
    }
}

__global__ void bnfinal_kernel(const float* __restrict__ part, float* __restrict__ bnbuf,
                               const float* __restrict__ gamma, const float* __restrict__ beta,
                               int N) {
    __shared__ float sums[128];
    int t = threadIdx.x;  // 128 threads
    float s = 0.f;
    for (int b = 0; b < 256; ++b) s += part[b * 128 + t];
    sums[t] = s;
    __syncthreads();
    if (t < 64) {
        float invN = 1.f / (float)N;
        float mean = sums[t] * invN;
        float var = sums[64 + t] * invN - mean * mean;
        float inv = rsqrtf(var + 1e-5f);
        float scale = gamma[t] * inv;
        bnbuf[t] = scale;
        bnbuf[64 + t] = beta[t] - mean * scale;
    }
}

// BN apply + leaky + residual; optionally computes gate[n] (no atomics!)
__global__ __launch_bounds__(256) void bnapply_kernel(
    const float* __restrict__ outbuf, const float* __restrict__ bnbuf,
    const float* __restrict__ gate_W, const float* __restrict__ gate_b,
    float* __restrict__ h, ushort_t* __restrict__ h_bf,
    float* __restrict__ gatebuf, int do_pool, int N) {
    int idx = blockIdx.x * 256 + threadIdx.x;
    if (idx >= N * 64) return;
    int c = idx & 63, n = idx >> 6;
    float o = outbuf[idx] * bnbuf[c] + bnbuf[64 + c];
    o = (o > 0.f) ? o : 0.01f * o;
    float hn = h[idx] + o;
    h[idx] = hn;
    h_bf[idx] = f2bf(hn);
    if (do_pool) {
        float g = hn * gate_W[c];
#pragma unroll
        for (int off = 32; off; off >>= 1) g += __shfl_xor(g, off);
        if (c == 0) gatebuf[n] = g + gate_b[0];
    }
}

// ---------------- pooling: per-graph max (no atomics) -> chunked acc -> finalize ----

__global__ __launch_bounds__(256) void pool_max_kernel(const float* __restrict__ gatebuf,
                                                       const int* __restrict__ batch,
                                                       float* __restrict__ m, int N) {
    int b = blockIdx.x;
    int lo = 0, hi = N;
    while (lo < hi) { int mid = (lo + hi) >> 1; if (batch[mid] < b) lo = mid + 1; else hi = mid; }
    int start = lo;
    lo = start; hi = N;
    while (lo < hi) { int mid = (lo + hi) >> 1; if (batch[mid] <= b) lo = mid + 1; else hi = mid; }
    int end = lo;
    int t = threadIdx.x, lane = t & 63, wid = t >> 6;
    __shared__ float sm[4];
    float mx = -1e30f;
    for (int n = start + t; n < end; n += 256) mx = fmaxf(mx, gatebuf[n]);
#pragma unroll
    for (int off = 32; off; off >>= 1) mx = fmaxf(mx, __shfl_xor(mx, off));
    if (lane == 0) sm[wid] = mx;
    __syncthreads();
    if (t == 0) m[b] = fmaxf(fmaxf(sm[0], sm[1]), fmaxf(sm[2], sm[3]));
}

__global__ __launch_bounds__(256) void pool_acc_kernel(
    const float* __restrict__ h, const float* __restrict__ gatebuf,
    const int* __restrict__ batch, const float* __restrict__ gmax,
    float* __restrict__ pacc, float* __restrict__ pden, int N) {
    int b = blockIdx.x >> 3, chunk = blockIdx.x & 7;
    int lo = 0, hi = N;
    while (lo < hi) { int mid = (lo + hi) >> 1; if (batch[mid] < b) lo = mid + 1; else hi = mid; }
    int start = lo;
    lo = start; hi = N;
    while (lo < hi) { int mid = (lo + hi) >> 1; if (batch[mid] <= b) lo = mid + 1; else hi = mid; }
    int end = lo;
    int lane = threadIdx.x & 63, wid = threadIdx.x >> 6;
    int gwid = chunk * 4 + wid;
    float mb = gmax[b];
    float acc = 0.f, den = 0.f;
    for (int n = start + gwid; n < end; n += 32) {
        float ge = __expf(gatebuf[n] - mb);
        acc += ge * h[(size_t)n * 64 + lane];
        den += ge;
    }
    __shared__ float sacc[4][64];
    __shared__ float sden[4];
    sacc[wid][lane] = acc;
    if (lane == 0) sden[wid] = den;
    __syncthreads();
    if (wid == 0) {
        pacc[(size_t)blockIdx.x * 64 + lane] =
            sacc[0][lane] + sacc[1][lane] + sacc[2][lane] + sacc[3][lane];
        if (lane == 0) pden[blockIdx.x] = sden[0] + sden[1] + sden[2] + sden[3];
    }
}

__global__ void pool_fin_kernel(const float* __restrict__ pacc, const float* __restrict__ pden,
                                const float* __restrict__ out_W, const float* __restrict__ out_b,
                                float* __restrict__ out) {
    int b = blockIdx.x, c = threadIdx.x;
    float pc = 0.f, dv = 0.f;
#pragma unroll
    for (int j = 0; j < 8; ++j) {
        pc += pacc[(size_t)(b * 8 + j) * 64 + c];
        dv += pden[b * 8 + j];
    }
    float s = pc * out_W[c];
#pragma unroll
    for (int off = 32; off; off >>= 1) s += __shfl_xor(s, off);
    if (c == 0) {
        if (dv <= 0.f) dv = 1.f;
        float v = s / dv + out_b[0];
        out[b] = 1.f / (1.f + __expf(-v));
    }
}

// ---------------- host ----------------

extern "C" void kernel_launch(void* const* d_in, const int* in_sizes, int n_in,
                              void* d_out, int out_size, void* d_ws, size_t ws_size,
                              hipStream_t stream) {
    const float* x         = (const float*)d_in[0];
    const float* edge_attr = (const float*)d_in[1];
    const int*   edge_src  = (const int*)d_in[2];
    const int*   edge_dst  = (const int*)d_in[3];
    const int*   batch     = (const int*)d_in[4];
    const float* node_W    = (const float*)d_in[5];
    const float* node_b    = (const float*)d_in[6];
    const float* edge_W    = (const float*)d_in[7];
    const float* edge_b    = (const float*)d_in[8];
    const float* Wq        = (const float*)d_in[9];
    const float* bq        = (const float*)d_in[10];
    const float* Wk        = (const float*)d_in[11];
    const float* bk        = (const float*)d_in[12];
    const float* Wv        = (const float*)d_in[13];
    const float* bv        = (const float*)d_in[14];
    const float* We        = (const float*)d_in[15];
    const float* be        = (const float*)d_in[16];
    const float* Wskip     = (const float*)d_in[17];
    const float* bskip     = (const float*)d_in[18];
    const float* gamma     = (const float*)d_in[19];
    const float* beta      = (const float*)d_in[20];
    const float* gate_W    = (const float*)d_in[21];
    const float* gate_b    = (const float*)d_in[22];
    const float* out_W     = (const float*)d_in[23];
    const float* out_b     = (const float*)d_in[24];
    float* out = (float*)d_out;

    const int N = in_sizes[0] / 16;
    const int E = in_sizes[2];

    char* ws = (char*)d_ws;
    size_t off = 0;
    auto alloc = [&](size_t bytes) {
        size_t o = off;
        off += (bytes + 255) & ~(size_t)255;
        return o;
    };
    float*    h        = (float*)(ws + alloc((size_t)N * 64 * 4));
    ushort_t* h_bf     = (ushort_t*)(ws + alloc((size_t)N * 64 * 2));
    ushort_t* qkv      = (ushort_t*)(ws + alloc((size_t)N * 384 * 2));
    float*    outbuf   = (float*)(ws + alloc((size_t)N * 64 * 4));
    float*    qcbuf    = (float*)(ws + alloc((size_t)N * 20 * 4));
    int*      rowptr   = (int*)(ws + alloc((size_t)(N + 1) * 4));
    int*      cursor   = (int*)(ws + alloc((size_t)N * 4));
    int*      counts   = (int*)(ws + alloc((size_t)N * 4));
    int*      bsums    = (int*)(ws + alloc(1024));
    int*      csr_src  = (int*)(ws + alloc((size_t)E * 4));
    float*    ea_perm  = (float*)(ws + alloc((size_t)E * 8 * 4));
    float*    Wc       = (float*)(ws + alloc(2 * 1024 * 4));
    float*    bcb      = (float*)(ws + alloc(2 * 128 * 4));
    float*    Wqc      = (float*)(ws + alloc(2 * 1152 * 4));
    float*    bias18   = (float*)(ws + alloc(2 * 18 * 4));
    ushort_t* Wall_arr = (ushort_t*)(ws + alloc(2 * 28672 * 2));
    float*    Wall_b   = (float*)(ws + alloc(2 * 448 * 4));
    float*    bnbuf    = (float*)(ws + alloc(128 * 4));
    float*    gatebuf  = (float*)(ws + alloc((size_t)N * 4));
    float*    gmax     = (float*)(ws + alloc(64 * 4));
    float*    pacc     = (float*)(ws + alloc(512 * 64 * 4));
    float*    pden     = (float*)(ws + alloc(512 * 4));
    if (off > ws_size) return;

    int O0 = (N * 64 + 255) / 256;
    int O1 = O0 + (N + 255) / 256;
    int O2 = O1 + 9;
    int O3 = O2 + 228;
    setup_kernel<<<O3, 256, 0, stream>>>(
        x, node_W, node_b, edge_W, edge_b, We, be, Wq, bq, Wk, bk, Wv, bv, Wskip, bskip,
        h, h_bf, counts, Wc, bcb, Wall_arr, Wall_b, O0, O1, O2, N);
    combine2_kernel<<<10, 256, 0, stream>>>(Wq, bq, Wc, bcb, Wqc, bias18);

    csr_count_kernel<<<(E + 255) / 256, 256, 0, stream>>>(edge_dst, counts, E);
    int nb = (N + 255) / 256;
    scan1_kernel<<<nb, 256, 0, stream>>>(counts, rowptr, bsums, N);
    scan2_kernel<<<1, 256, 0, stream>>>(bsums, nb);
    scan3_kernel<<<nb, 256, 0, stream>>>(rowptr, bsums, cursor, N, E);
    csr_fill_kernel<<<(E + 255) / 256, 256, 0, stream>>>(edge_dst, edge_src, edge_attr,
                                                         cursor, csr_src, ea_perm, E);

    for (int l = 0; l < 2; ++l) {
        qkvqc_kernel<<<dim3((N + 15) / 16, 2), 256, 0, stream>>>(
            h, h_bf, Wall_arr + (size_t)l * 28672, Wall_b + l * 448,
            Wqc + l * 1152, bias18 + l * 18, qkv, outbuf, qcbuf, N);
        attn_kernel<<<(N + 3) / 4, 256, 0, stream>>>(qkv, qcbuf, csr_src, ea_perm,
                                                     rowptr, Wc + l * 1024,
                                                     bcb + l * 128, outbuf, N);
        bnstats_kernel<<<256, 256, 0, stream>>>(outbuf, pacc, N);
        bnfinal_kernel<<<1, 128, 0, stream>>>(pacc, bnbuf, gamma + l * 64, beta + l * 64, N);
        bnapply_kernel<<<(N * 64 + 255) / 256, 256, 0, stream>>>(
            outbuf, bnbuf, gate_W, gate_b, h, h_bf, gatebuf, (l == 1) ? 1 : 0, N);
    }

    pool_max_kernel<<<64, 256, 0, stream>>>(gatebuf, batch, gmax, N);
    pool_acc_kernel<<<512, 256, 0, stream>>>(h, gatebuf, batch, gmax, pacc, pden, N);
    pool_fin_kernel<<<64, 64, 0, stream>>>(pacc, pden, out_W, out_b, out);
}

// Round 10
// 528.260 us; speedup vs baseline: 2.4104x; 1.0077x over previous
//
#include <hip/hip_runtime.h>
#include <hip/hip_bf16.h>

typedef unsigned short ushort_t;
typedef __attribute__((ext_vector_type(8))) short short8;
typedef __attribute__((ext_vector_type(4))) float float4v;

__device__ __forceinline__ float bfu(unsigned u) {
    return __uint_as_float(u << 16);
}
__device__ __forceinline__ float bfu_lo(unsigned u) {   // low ushort of packed pair
    return __uint_as_float(u << 16);
}
__device__ __forceinline__ float bfu_hi(unsigned u) {   // high ushort: free AND
    return __uint_as_float(u & 0xffff0000u);
}
__device__ __forceinline__ ushort_t f2bf(float f) {
    __hip_bfloat16 h = __float2bfloat16(f);
    return *reinterpret_cast<ushort_t*>(&h);
}

// Wall layout per layer: 30 col-tiles (cols 0..479; 466 used), tile ct = 1024 ushorts:
//   idx = ct*1024 + kch*512 + lane*8 + j   (kch = K-chunk 0/1)
// cols: 0..127 q | 128..255 k | 256..383 v | 384..447 skip | 448..465 qc(+bias18)

// ---------------- fused setup: node_enc + zeroing + combine_w + prep_w ----------------

__global__ __launch_bounds__(256) void setup_kernel(
    const float* __restrict__ x, const float* __restrict__ node_W,
    const float* __restrict__ node_b,
    const float* __restrict__ edge_W, const float* __restrict__ edge_b,
    const float* __restrict__ We, const float* __restrict__ be,
    const float* __restrict__ Wq, const float* __restrict__ bq,
    const float* __restrict__ Wk, const float* __restrict__ bk,
    const float* __restrict__ Wv, const float* __restrict__ bv,
    const float* __restrict__ Wskip, const float* __restrict__ bskip,
    float* __restrict__ h, ushort_t* __restrict__ h_bf,
    int* __restrict__ counts,
    float* __restrict__ Wc, float* __restrict__ bcb,
    ushort_t* __restrict__ Wall_arr, float* __restrict__ Wall_bias,
    int O0, int O1, int O2, int N) {
    int b = blockIdx.x, t = threadIdx.x;
    if (b < O0) {
        int idx = b * 256 + t;
        if (idx < N * 64) {
            int n = idx >> 6, c = idx & 63;
            float acc = node_b[c];
#pragma unroll
            for (int j = 0; j < 16; ++j) acc += x[n * 16 + j] * node_W[j * 64 + c];
            h[idx] = acc;
            h_bf[idx] = f2bf(acc);
        }
    } else if (b < O1) {
        int i = (b - O0) * 256 + t;
        if (i < N) counts[i] = 0;
    } else if (b < O2) {
        int tid = (b - O1) * 256 + t;
        if (tid < 2048) {
            int l = tid >> 10, d = (tid >> 7) & 7, j = tid & 127;
            float s = 0.f;
            for (int m = 0; m < 64; ++m) s += edge_W[d * 64 + m] * We[l * 8192 + m * 128 + j];
            Wc[l * 1024 + d * 128 + j] = s;
        } else if (tid < 2048 + 256) {
            int u = tid - 2048;
            int l = u >> 7, j = u & 127;
            float s = be[l * 128 + j];
            for (int m = 0; m < 64; ++m) s += edge_b[m] * We[l * 8192 + m * 128 + j];
            bcb[l * 128 + j] = s;
        }
    } else {
        int tid = (b - O2) * 256 + t;
        if (tid < 2 * 28672) {
            int l = tid / 28672, u = tid % 28672;
            int j = u & 7, ln = (u >> 3) & 63, kch = (u >> 9) & 1, ct = u >> 10;  // ct 0..27
            int nn = ln & 15, quad = ln >> 4;
            int k = kch * 32 + quad * 8 + j;
            int col = ct * 16 + nn;
            float v;
            if (col < 128)      v = Wq[l * 8192 + k * 128 + col];
            else if (col < 256) v = Wk[l * 8192 + k * 128 + col - 128];
            else if (col < 384) v = Wv[l * 8192 + k * 128 + col - 256];
            else                v = Wskip[l * 4096 + k * 64 + col - 384];
            Wall_arr[(size_t)l * 32768 + ct * 1024 + kch * 512 + ln * 8 + j] = f2bf(v);
        } else if (tid < 2 * 28672 + 2 * 448) {
            int u = tid - 2 * 28672;
            int l = u / 448, col = u % 448;
            float v;
            if (col < 128)      v = bq[l * 128 + col];
            else if (col < 256) v = bk[l * 128 + col - 128];
            else if (col < 384) v = bv[l * 128 + col - 256];
            else                v = bskip[l * 64 + col - 384];
            Wall_bias[l * 512 + col] = v;
        }
    }
}

// combine2: qc weights (0.125 * Wq·Wc composition) written directly into Wall fragments
__global__ void combine2_kernel(const float* __restrict__ Wq, const float* __restrict__ bq,
                                const float* __restrict__ Wc, const float* __restrict__ bcb,
                                ushort_t* __restrict__ Wall_arr, float* __restrict__ Wall_bias) {
    int tid = blockIdx.x * 256 + threadIdx.x;
    if (tid < 2304) {
        int l = tid / 1152, u = tid % 1152, k = u / 18, j = u % 18;
        float s = 0.f;
        if (j < 16) {
            int hh = j >> 3, d = j & 7;
            for (int c = 0; c < 64; ++c)
                s += Wq[l * 8192 + k * 128 + hh * 64 + c] * Wc[l * 1024 + d * 128 + hh * 64 + c];
        } else {
            int hh = j - 16;
            for (int c = 0; c < 64; ++c)
                s += Wq[l * 8192 + k * 128 + hh * 64 + c] * bcb[l * 128 + hh * 64 + c];
        }
        s *= 0.125f;
        int col = 448 + j;
        int ct = col >> 4, nn = col & 15;
        int kch = k >> 5, quad = (k >> 3) & 3, jj = k & 7;
        int ln = quad * 16 + nn;
        Wall_arr[(size_t)l * 32768 + ct * 1024 + kch * 512 + ln * 8 + jj] = f2bf(s);
    } else if (tid < 2304 + 36) {
        int u = tid - 2304;
        int l = u / 18, j = u % 18;
        float s = 0.f;
        if (j < 16) {
            int hh = j >> 3, d = j & 7;
            for (int c = 0; c < 64; ++c)
                s += bq[l * 128 + hh * 64 + c] * Wc[l * 1024 + d * 128 + hh * 64 + c];
        } else {
            int hh = j - 16;
            for (int c = 0; c < 64; ++c)
                s += bq[l * 128 + hh * 64 + c] * bcb[l * 128 + hh * 64 + c];
        }
        Wall_bias[l * 512 + 448 + j] = 0.125f * s;
    }
}

// ---------------- CSR build (by dst) with byte-offset src + edge_attr permutation ----

__global__ void csr_count_kernel(const int* __restrict__ dst, int* __restrict__ counts, int E) {
    int e = blockIdx.x * 256 + threadIdx.x;
    if (e < E) atomicAdd(&counts[dst[e]], 1);
}

__global__ void scan1_kernel(const int* __restrict__ counts, int* __restrict__ rowptr,
                             int* __restrict__ bsums, int N) {
    __shared__ int s[256];
    int t = threadIdx.x, i = blockIdx.x * 256 + t;
    int v = (i < N) ? counts[i] : 0;
    s[t] = v;
    __syncthreads();
    for (int d = 1; d < 256; d <<= 1) {
        int x = (t >= d) ? s[t - d] : 0;
        __syncthreads();
        s[t] += x;
        __syncthreads();
    }
    if (i < N) rowptr[i] = s[t] - v;
    if (t == 255) bsums[blockIdx.x] = s[255];
}

__global__ void scan2_kernel(int* __restrict__ bsums, int nb) {
    __shared__ int s[256];
    int t = threadIdx.x;
    int v = (t < nb) ? bsums[t] : 0;
    s[t] = v;
    __syncthreads();
    for (int d = 1; d < 256; d <<= 1) {
        int x = (t >= d) ? s[t - d] : 0;
        __syncthreads();
        s[t] += x;
        __syncthreads();
    }
    if (t < nb) bsums[t] = s[t] - v;
}

__global__ void scan3_kernel(int* __restrict__ rowptr, const int* __restrict__ bsums,
                             int* __restrict__ cursor, int N, int E) {
    int i = blockIdx.x * 256 + threadIdx.x;
    if (i < N) {
        int r = rowptr[i] + bsums[i >> 8];
        rowptr[i] = r;
        cursor[i] = r;
    }
    if (i == 0) rowptr[N] = E;
}

// fill: store BYTE OFFSET of kv region (src*768 + 256) + permute edge_attr
__global__ void csr_fill_kernel(const int* __restrict__ dst, const int* __restrict__ src,
                                const float* __restrict__ edge_attr, int* __restrict__ cursor,
                                int* __restrict__ csr_src, float* __restrict__ ea_perm, int E) {
    int e = blockIdx.x * 256 + threadIdx.x;
    if (e < E) {
        int pos = atomicAdd(&cursor[dst[e]], 1);
        csr_src[pos] = src[e] * 768 + 256;
        float4 a0 = *(const float4*)(edge_attr + (size_t)e * 8);
        float4 a1 = *(const float4*)(edge_attr + (size_t)e * 8 + 4);
        *(float4*)(ea_perm + (size_t)pos * 8) = a0;
        *(float4*)(ea_perm + (size_t)pos * 8 + 4) = a1;
    }
}

// ---------------- per-layer MFMA GEMM: [16 nodes x 64] @ [64 x 466] ----------------
// cols 0..383 -> qkv bf16 (k/v interleaved); 384..447 -> outbuf (skip); 448..465 -> qcbuf

__global__ __launch_bounds__(256) void qkv_mfma_kernel(
    const ushort_t* __restrict__ h_bf,
    const ushort_t* __restrict__ Wall_arr, const float* __restrict__ Wall_bias,
    ushort_t* __restrict__ qkv, float* __restrict__ outbuf, float* __restrict__ qcbuf, int N) {
    int wave = threadIdx.x >> 6, lane = threadIdx.x & 63;
    int quad = lane >> 4, nn = lane & 15;
    int n0 = blockIdx.x * 16;
    int node_a = n0 + nn;
    if (node_a >= N) node_a = N - 1;
    const ushort_t* ap = h_bf + (size_t)node_a * 64 + quad * 8;
    short8 a0 = *(const short8*)ap;
    short8 a1 = *(const short8*)(ap + 32);
    int ct_start = (wave < 2) ? wave * 8 : (16 + (wave - 2) * 7);
    int ct_cnt = (wave < 2) ? 8 : 7;
    for (int i = 0; i < ct_cnt; ++i) {
        int ct = ct_start + i;
        const ushort_t* bp = Wall_arr + (size_t)ct * 1024 + lane * 8;
        short8 b0 = *(const short8*)bp;
        short8 b1 = *(const short8*)(bp + 512);
        float4v c = {0.f, 0.f, 0.f, 0.f};
        c = __builtin_amdgcn_mfma_f32_16x16x32_bf16(a0, b0, c, 0, 0, 0);
        c = __builtin_amdgcn_mfma_f32_16x16x32_bf16(a1, b1, c, 0, 0, 0);
        int col = ct * 16 + nn;
        float bias = Wall_bias[col];
        if (col < 384) {
            int cm;
            if (col < 128) cm = col;
            else if (col < 256) { int cc = col - 128; cm = 128 + ((cc >> 1) << 2) + (cc & 1); }
            else { int cc = col - 256; cm = 128 + ((cc >> 1) << 2) + 2 + (cc & 1); }
            ushort_t* qp = qkv + (size_t)(n0 + quad * 4) * 384 + cm;
#pragma unroll
            for (int r = 0; r < 4; ++r)
                if (n0 + quad * 4 + r < N) qp[(size_t)r * 384] = f2bf(c[r] + bias);
        } else if (col < 448) {
            float* op = outbuf + (size_t)(n0 + quad * 4) * 64 + (col - 448 + 64);
#pragma unroll
            for (int r = 0; r < 4; ++r)
                if (n0 + quad * 4 + r < N) op[(size_t)r * 64] = c[r] + bias;
        } else if (col < 466) {
            float* qp2 = qcbuf + (size_t)(n0 + quad * 4) * 20 + (col - 448);
#pragma unroll
            for (int r = 0; r < 4; ++r)
                if (n0 + quad * 4 + r < N) qp2[(size_t)r * 20] = c[r] + bias;
        }
    }
}

// ---------------- attention ----------------

__global__ __launch_bounds__(256) void attn_kernel(
    const ushort_t* __restrict__ qkv, const float* __restrict__ qcbuf,
    const int* __restrict__ csr_src, const float* __restrict__ ea_perm,
    const int* __restrict__ rowptr,
    const float* __restrict__ Wc, const float* __restrict__ bcb,
    float* __restrict__ outbuf, int N) {
    __shared__ float Wc_s[1024];
    __shared__ float bc_s[128];
    int t = threadIdx.x;
    for (int i = t; i < 1024; i += 256) Wc_s[i] = Wc[i];
    if (t < 128) bc_s[t] = bcb[t];
    __syncthreads();
    int lane = t & 63, wid = t >> 6;
    int half = lane >> 5, l31 = lane & 31;
    const char* qkvb = (const char*)qkv;
    for (int n = blockIdx.x * 4 + wid; n < N; n += gridDim.x * 4) {
        int start = rowptr[n], end = rowptr[n + 1];
        if (end <= start) continue;  // outbuf already holds skip
        unsigned qraw = *(const unsigned*)(qkvb + (size_t)n * 768 + 4 * lane);
        float qx = bfu_lo(qraw), qy = bfu_hi(qraw);
        const float4 qcA = *(const float4*)(qcbuf + (size_t)n * 20 + half * 8);
        const float4 qcB = *(const float4*)(qcbuf + (size_t)n * 20 + half * 8 + 4);
        float qb = qcbuf[(size_t)n * 20 + 16 + half];
        float lsum = 0.f, ax = 0.f, ay = 0.f;
        float4 se0 = {0.f, 0.f, 0.f, 0.f}, se1 = {0.f, 0.f, 0.f, 0.f};
        for (int seg = start; seg < end; seg += 64) {
            int segcnt = min(64, end - seg);
            int li = (lane < segcnt) ? lane : (segcnt - 1);
            int offL = csr_src[seg + li];     // kv byte offsets, one coalesced load
            uint2 kvc[4], kvn[4];
#pragma unroll
            for (int j = 0; j < 4; ++j) {
                int idx = (j < segcnt) ? j : (segcnt - 1);
                int o = __shfl(offL, idx);
                kvc[j] = *(const uint2*)(qkvb + (size_t)(unsigned)o + 8 * lane);
            }
            for (int base = 0; base < segcnt; base += 4) {
                int nb2 = base + 4;
                if (nb2 < segcnt) {
#pragma unroll
                    for (int j = 0; j < 4; ++j) {
                        int idx = (nb2 + j < segcnt) ? (nb2 + j) : (segcnt - 1);
                        int o = __shfl(offL, idx);
                        kvn[j] = *(const uint2*)(qkvb + (size_t)(unsigned)o + 8 * lane);
                    }
                }
                float4 a0[4], a1[4];
                float dt[4];
#pragma unroll
                for (int j = 0; j < 4; ++j) {
                    int gi = seg + base + ((base + j < segcnt) ? j : 0);
                    const float* eap = ea_perm + (size_t)gi * 8;
                    a0[j] = *(const float4*)eap;
                    a1[j] = *(const float4*)(eap + 4);
                    dt[j] = qx * bfu_lo(kvc[j].x) + qy * bfu_hi(kvc[j].x);
                }
#pragma unroll
                for (int m = 1; m <= 16; m <<= 1) {
#pragma unroll
                    for (int j = 0; j < 4; ++j) dt[j] += __shfl_xor(dt[j], m);
                }
#pragma unroll
                for (int j = 0; j < 4; ++j) {
                    float s0 = dt[j] * 0.125f
                        + qcA.x * a0[j].x + qcA.y * a0[j].y + qcA.z * a0[j].z + qcA.w * a0[j].w
                        + qcB.x * a1[j].x + qcB.y * a1[j].y + qcB.z * a1[j].z + qcB.w * a1[j].w
                        + qb;
                    float p = (base + j < segcnt) ? __expf(fmaxf(s0, -60.f)) : 0.f;
                    lsum += p;
                    ax += p * bfu_lo(kvc[j].y);
                    ay += p * bfu_hi(kvc[j].y);
                    se0.x += p * a0[j].x; se0.y += p * a0[j].y;
                    se0.z += p * a0[j].z; se0.w += p * a0[j].w;
                    se1.x += p * a1[j].x; se1.y += p * a1[j].y;
                    se1.z += p * a1[j].z; se1.w += p * a1[j].w;
                }
#pragma unroll
                for (int j = 0; j < 4; ++j) kvc[j] = kvn[j];
            }
        }
        int j0 = half * 64 + 2 * l31;
        float w0 = lsum * bc_s[j0], w1 = lsum * bc_s[j0 + 1];
        w0 += se0.x * Wc_s[0 * 128 + j0] + se0.y * Wc_s[1 * 128 + j0] +
              se0.z * Wc_s[2 * 128 + j0] + se0.w * Wc_s[3 * 128 + j0] +
              se1.x * Wc_s[4 * 128 + j0] + se1.y * Wc_s[5 * 128 + j0] +
              se1.z * Wc_s[6 * 128 + j0] + se1.w * Wc_s[7 * 128 + j0];
        w1 += se0.x * Wc_s[0 * 128 + j0 + 1] + se0.y * Wc_s[1 * 128 + j0 + 1] +
              se0.z * Wc_s[2 * 128 + j0 + 1] + se0.w * Wc_s[3 * 128 + j0 + 1] +
              se1.x * Wc_s[4 * 128 + j0 + 1] + se1.y * Wc_s[5 * 128 + j0 + 1] +
              se1.z * Wc_s[6 * 128 + j0 + 1] + se1.w * Wc_s[7 * 128 + j0 + 1];
        float inv = 1.f / lsum;
        float ox = (ax + w0) * inv, oy = (ay + w1) * inv;
        float px = __shfl_xor(ox, 32), py = __shfl_xor(oy, 32);
        ox = 0.5f * (ox + px);
        oy = 0.5f * (oy + py);
        if (half == 0) {
            float2* op = (float2*)(outbuf + (size_t)n * 64 + 2 * l31);
            float2 cur = *op;
            *op = make_float2(cur.x + ox, cur.y + oy);
        }
    }
}

// ---------------- BN: partial stats (grid 256) -> finalize -> apply ----------------

__global__ __launch_bounds__(256) void bnstats_kernel(const float* __restrict__ outbuf,
                                                      float* __restrict__ part, int N) {
    __shared__ float ssum[64], ssq[64];
    int t = threadIdx.x;
    if (t < 64) { ssum[t] = 0.f; ssq[t] = 0.f; }
    __syncthreads();
    float a = 0.f, b = 0.f;
    int idx0 = blockIdx.x * 256 + t;
    for (int idx = idx0; idx < N * 64; idx += 65536) {
        float v = outbuf[idx];
        a += v;
        b += v * v;
    }
    int c = t & 63;
    atomicAdd(&ssum[c], a);
    atomicAdd(&ssq[c], b);
    __syncthreads();
    if (t < 64) {
        part[blockIdx.x * 128 + t] = ssum[t];
        part[blockIdx.x * 128 + 64 + t] = ssq[t];
    }
}

__global__ void bnfinal_kernel(const float* __restrict__ part, float* __restrict__ bnbuf,
                               const float* __restrict__ gamma, const float* __restrict__ beta,
                               int N) {
    __shared__ float sums[128];
    int t = threadIdx.x;  // 128 threads
    float s = 0.f;
    for (int b = 0; b < 256; ++b) s += part[b * 128 + t];
    sums[t] = s;
    __syncthreads();
    if (t < 64) {
        float invN = 1.f / (float)N;
        float mean = sums[t] * invN;
        float var = sums[64 + t] * invN - mean * mean;
        float inv = rsqrtf(var + 1e-5f);
        float scale = gamma[t] * inv;
        bnbuf[t] = scale;
        bnbuf[64 + t] = beta[t] - mean * scale;
    }
}

// BN apply + leaky + residual; optionally computes gate[n] (no atomics)
__global__ __launch_bounds__(256) void bnapply_kernel(
    const float* __restrict__ outbuf, const float* __restrict__ bnbuf,
    const float* __restrict__ gate_W, const float* __restrict__ gate_b,
    float* __restrict__ h, ushort_t* __restrict__ h_bf,
    float* __restrict__ gatebuf, int do_pool, int N) {
    int idx = blockIdx.x * 256 + threadIdx.x;
    if (idx >= N * 64) return;
    int c = idx & 63, n = idx >> 6;
    float o = outbuf[idx] * bnbuf[c] + bnbuf[64 + c];
    o = (o > 0.f) ? o : 0.01f * o;
    float hn = h[idx] + o;
    h[idx] = hn;
    h_bf[idx] = f2bf(hn);
    if (do_pool) {
        float g = hn * gate_W[c];
#pragma unroll
        for (int off = 32; off; off >>= 1) g += __shfl_xor(g, off);
        if (c == 0) gatebuf[n] = g + gate_b[0];
    }
}

// ---------------- pooling: per-graph max (no atomics) -> chunked acc -> finalize ----

__global__ __launch_bounds__(256) void pool_max_kernel(const float* __restrict__ gatebuf,
                                                       const int* __restrict__ batch,
                                                       float* __restrict__ m, int N) {
    int b = blockIdx.x;
    int lo = 0, hi = N;
    while (lo < hi) { int mid = (lo + hi) >> 1; if (batch[mid] < b) lo = mid + 1; else hi = mid; }
    int start = lo;
    lo = start; hi = N;
    while (lo < hi) { int mid = (lo + hi) >> 1; if (batch[mid] <= b) lo = mid + 1; else hi = mid; }
    int end = lo;
    int t = threadIdx.x, lane = t & 63, wid = t >> 6;
    __shared__ float sm[4];
    float mx = -1e30f;
    for (int n = start + t; n < end; n += 256) mx = fmaxf(mx, gatebuf[n]);
#pragma unroll
    for (int off = 32; off; off >>= 1) mx = fmaxf(mx, __shfl_xor(mx, off));
    if (lane == 0) sm[wid] = mx;
    __syncthreads();
    if (t == 0) m[b] = fmaxf(fmaxf(sm[0], sm[1]), fmaxf(sm[2], sm[3]));
}

__global__ __launch_bounds__(256) void pool_acc_kernel(
    const float* __restrict__ h, const float* __restrict__ gatebuf,
    const int* __restrict__ batch, const float* __restrict__ gmax,
    float* __restrict__ pacc, float* __restrict__ pden, int N) {
    int b = blockIdx.x >> 3, chunk = blockIdx.x & 7;
    int lo = 0, hi = N;
    while (lo < hi) { int mid = (lo + hi) >> 1; if (batch[mid] < b) lo = mid + 1; else hi = mid; }
    int start = lo;
    lo = start; hi = N;
    while (lo < hi) { int mid = (lo + hi) >> 1; if (batch[mid] <= b) lo = mid + 1; else hi = mid; }
    int end = lo;
    int lane = threadIdx.x & 63, wid = threadIdx.x >> 6;
    int gwid = chunk * 4 + wid;
    float mb = gmax[b];
    float acc = 0.f, den = 0.f;
    for (int n = start + gwid; n < end; n += 32) {
        float ge = __expf(gatebuf[n] - mb);
        acc += ge * h[(size_t)n * 64 + lane];
        den += ge;
    }
    __shared__ float sacc[4][64];
    __shared__ float sden[4];
    sacc[wid][lane] = acc;
    if (lane == 0) sden[wid] = den;
    __syncthreads();
    if (wid == 0) {
        pacc[(size_t)blockIdx.x * 64 + lane] =
            sacc[0][lane] + sacc[1][lane] + sacc[2][lane] + sacc[3][lane];
        if (lane == 0) pden[blockIdx.x] = sden[0] + sden[1] + sden[2] + sden[3];
    }
}

__global__ void pool_fin_kernel(const float* __restrict__ pacc, const float* __restrict__ pden,
                                const float* __restrict__ out_W, const float* __restrict__ out_b,
                                float* __restrict__ out) {
    int b = blockIdx.x, c = threadIdx.x;
    float pc = 0.f, dv = 0.f;
#pragma unroll
    for (int j = 0; j < 8; ++j) {
        pc += pacc[(size_t)(b * 8 + j) * 64 + c];
        dv += pden[b * 8 + j];
    }
    float s = pc * out_W[c];
#pragma unroll
    for (int off = 32; off; off >>= 1) s += __shfl_xor(s, off);
    if (c == 0) {
        if (dv <= 0.f) dv = 1.f;
        float v = s / dv + out_b[0];
        out[b] = 1.f / (1.f + __expf(-v));
    }
}

// ---------------- host ----------------

extern "C" void kernel_launch(void* const* d_in, const int* in_sizes, int n_in,
                              void* d_out, int out_size, void* d_ws, size_t ws_size,
                              hipStream_t stream) {
    const float* x         = (const float*)d_in[0];
    const float* edge_attr = (const float*)d_in[1];
    const int*   edge_src  = (const int*)d_in[2];
    const int*   edge_dst  = (const int*)d_in[3];
    const int*   batch     = (const int*)d_in[4];
    const float* node_W    = (const float*)d_in[5];
    const float* node_b    = (const float*)d_in[6];
    const float* edge_W    = (const float*)d_in[7];
    const float* edge_b    = (const float*)d_in[8];
    const float* Wq        = (const float*)d_in[9];
    const float* bq        = (const float*)d_in[10];
    const float* Wk        = (const float*)d_in[11];
    const float* bk        = (const float*)d_in[12];
    const float* Wv        = (const float*)d_in[13];
    const float* bv        = (const float*)d_in[14];
    const float* We        = (const float*)d_in[15];
    const float* be        = (const float*)d_in[16];
    const float* Wskip     = (const float*)d_in[17];
    const float* bskip     = (const float*)d_in[18];
    const float* gamma     = (const float*)d_in[19];
    const float* beta      = (const float*)d_in[20];
    const float* gate_W    = (const float*)d_in[21];
    const float* gate_b    = (const float*)d_in[22];
    const float* out_W     = (const float*)d_in[23];
    const float* out_b     = (const float*)d_in[24];
    float* out = (float*)d_out;

    const int N = in_sizes[0] / 16;
    const int E = in_sizes[2];

    char* ws = (char*)d_ws;
    size_t off = 0;
    auto alloc = [&](size_t bytes) {
        size_t o = off;
        off += (bytes + 255) & ~(size_t)255;
        return o;
    };
    float*    h        = (float*)(ws + alloc((size_t)N * 64 * 4));
    ushort_t* h_bf     = (ushort_t*)(ws + alloc((size_t)N * 64 * 2));
    ushort_t* qkv      = (ushort_t*)(ws + alloc((size_t)N * 384 * 2));
    float*    outbuf   = (float*)(ws + alloc((size_t)N * 64 * 4));
    float*    qcbuf    = (float*)(ws + alloc((size_t)N * 20 * 4));
    int*      rowptr   = (int*)(ws + alloc((size_t)(N + 1) * 4));
    int*      cursor   = (int*)(ws + alloc((size_t)N * 4));
    int*      counts   = (int*)(ws + alloc((size_t)N * 4));
    int*      bsums    = (int*)(ws + alloc(1024));
    int*      csr_src  = (int*)(ws + alloc((size_t)E * 4));
    float*    ea_perm  = (float*)(ws + alloc((size_t)E * 8 * 4));
    float*    Wc       = (float*)(ws + alloc(2 * 1024 * 4));
    float*    bcb      = (float*)(ws + alloc(2 * 128 * 4));
    ushort_t* Wall_arr = (ushort_t*)(ws + alloc(2 * 32768 * 2));
    float*    Wall_b   = (float*)(ws + alloc(2 * 512 * 4));
    float*    bnbuf    = (float*)(ws + alloc(128 * 4));
    float*    gatebuf  = (float*)(ws + alloc((size_t)N * 4));
    float*    gmax     = (float*)(ws + alloc(64 * 4));
    float*    pacc     = (float*)(ws + alloc(512 * 64 * 4));
    float*    pden     = (float*)(ws + alloc(512 * 4));
    if (off > ws_size) return;

    int O0 = (N * 64 + 255) / 256;
    int O1 = O0 + (N + 255) / 256;
    int O2 = O1 + 9;
    int O3 = O2 + 228;
    setup_kernel<<<O3, 256, 0, stream>>>(
        x, node_W, node_b, edge_W, edge_b, We, be, Wq, bq, Wk, bk, Wv, bv, Wskip, bskip,
        h, h_bf, counts, Wc, bcb, Wall_arr, Wall_b, O0, O1, O2, N);
    combine2_kernel<<<10, 256, 0, stream>>>(Wq, bq, Wc, bcb, Wall_arr, Wall_b);

    csr_count_kernel<<<(E + 255) / 256, 256, 0, stream>>>(edge_dst, counts, E);
    int nb = (N + 255) / 256;
    scan1_kernel<<<nb, 256, 0, stream>>>(counts, rowptr, bsums, N);
    scan2_kernel<<<1, 256, 0, stream>>>(bsums, nb);
    scan3_kernel<<<nb, 256, 0, stream>>>(rowptr, bsums, cursor, N, E);
    csr_fill_kernel<<<(E + 255) / 256, 256, 0, stream>>>(edge_dst, edge_src, edge_attr,
                                                         cursor, csr_src, ea_perm, E);

    for (int l = 0; l < 2; ++l) {
        qkv_mfma_kernel<<<(N + 15) / 16, 256, 0, stream>>>(
            h_bf, Wall_arr + (size_t)l * 32768, Wall_b + l * 512, qkv, outbuf, qcbuf, N);
        attn_kernel<<<(N + 3) / 4, 256, 0, stream>>>(qkv, qcbuf, csr_src, ea_perm,
                                                     rowptr, Wc + l * 1024,
                                                     bcb + l * 128, outbuf, N);
        bnstats_kernel<<<256, 256, 0, stream>>>(outbuf, pacc, N);
        bnfinal_kernel<<<1, 128, 0, stream>>>(pacc, bnbuf, gamma + l * 64, beta + l * 64, N);
        bnapply_kernel<<<(N * 64 + 255) / 256, 256, 0, stream>>>(
            outbuf, bnbuf, gate_W, gate_b, h, h_bf, gatebuf, (l == 1) ? 1 : 0, N);
    }

    pool_max_kernel<<<64, 256, 0, stream>>>(gatebuf, batch, gmax, N);
    pool_acc_kernel<<<512, 256, 0, stream>>>(h, gatebuf, batch, gmax, pacc, pden, N);
    pool_fin_kernel<<<64, 64, 0, stream>>>(pacc, pden, out_W, out_b, out);
}

// Round 11
// 461.802 us; speedup vs baseline: 2.7573x; 1.1439x over previous
//
#include <hip/hip_runtime.h>
#include <hip/hip_bf16.h>

typedef unsigned short ushort_t;
typedef __attribute__((ext_vector_type(8))) short short8;
typedef __attribute__((ext_vector_type(4))) float float4v;

#define ATTN_BLOCKS 2048

__device__ __forceinline__ float bfu_lo(unsigned u) {
    return __uint_as_float(u << 16);
}
__device__ __forceinline__ float bfu_hi(unsigned u) {
    return __uint_as_float(u & 0xffff0000u);
}
__device__ __forceinline__ ushort_t f2bf(float f) {
    __hip_bfloat16 h = __float2bfloat16(f);
    return *reinterpret_cast<ushort_t*>(&h);
}

// Wall layout per layer: 30 col-tiles (466 cols used), tile = 1024 ushorts:
//   idx = ct*1024 + kch*512 + lane*8 + j
// cols: 0..127 q | 128..255 k | 256..383 v | 384..447 skip | 448..465 qc

// ---------------- fused setup ----------------

__global__ __launch_bounds__(256) void setup_kernel(
    const float* __restrict__ x, const float* __restrict__ node_W,
    const float* __restrict__ node_b,
    const float* __restrict__ edge_W, const float* __restrict__ edge_b,
    const float* __restrict__ We, const float* __restrict__ be,
    const float* __restrict__ Wq, const float* __restrict__ bq,
    const float* __restrict__ Wk, const float* __restrict__ bk,
    const float* __restrict__ Wv, const float* __restrict__ bv,
    const float* __restrict__ Wskip, const float* __restrict__ bskip,
    float* __restrict__ h, ushort_t* __restrict__ h_bf,
    int* __restrict__ counts,
    float* __restrict__ Wc, float* __restrict__ bcb,
    ushort_t* __restrict__ Wall_arr, float* __restrict__ Wall_bias,
    int O0, int O1, int O2, int N) {
    int b = blockIdx.x, t = threadIdx.x;
    if (b < O0) {
        int idx = b * 256 + t;
        if (idx < N * 64) {
            int n = idx >> 6, c = idx & 63;
            float acc = node_b[c];
#pragma unroll
            for (int j = 0; j < 16; ++j) acc += x[n * 16 + j] * node_W[j * 64 + c];
            h[idx] = acc;
            h_bf[idx] = f2bf(acc);
        }
    } else if (b < O1) {
        int i = (b - O0) * 256 + t;
        if (i < N) counts[i] = 0;
    } else if (b < O2) {
        int tid = (b - O1) * 256 + t;
        if (tid < 2048) {
            int l = tid >> 10, d = (tid >> 7) & 7, j = tid & 127;
            float s = 0.f;
            for (int m = 0; m < 64; ++m) s += edge_W[d * 64 + m] * We[l * 8192 + m * 128 + j];
            Wc[l * 1024 + d * 128 + j] = s;
        } else if (tid < 2048 + 256) {
            int u = tid - 2048;
            int l = u >> 7, j = u & 127;
            float s = be[l * 128 + j];
            for (int m = 0; m < 64; ++m) s += edge_b[m] * We[l * 8192 + m * 128 + j];
            bcb[l * 128 + j] = s;
        }
    } else {
        int tid = (b - O2) * 256 + t;
        if (tid < 2 * 28672) {
            int l = tid / 28672, u = tid % 28672;
            int j = u & 7, ln = (u >> 3) & 63, kch = (u >> 9) & 1, ct = u >> 10;
            int nn = ln & 15, quad = ln >> 4;
            int k = kch * 32 + quad * 8 + j;
            int col = ct * 16 + nn;
            float v;
            if (col < 128)      v = Wq[l * 8192 + k * 128 + col];
            else if (col < 256) v = Wk[l * 8192 + k * 128 + col - 128];
            else if (col < 384) v = Wv[l * 8192 + k * 128 + col - 256];
            else                v = Wskip[l * 4096 + k * 64 + col - 384];
            Wall_arr[(size_t)l * 32768 + ct * 1024 + kch * 512 + ln * 8 + j] = f2bf(v);
        } else if (tid < 2 * 28672 + 2 * 448) {
            int u = tid - 2 * 28672;
            int l = u / 448, col = u % 448;
            float v;
            if (col < 128)      v = bq[l * 128 + col];
            else if (col < 256) v = bk[l * 128 + col - 128];
            else if (col < 384) v = bv[l * 128 + col - 256];
            else                v = bskip[l * 64 + col - 384];
            Wall_bias[l * 512 + col] = v;
        }
    }
}

// combine2: qc composed weights into Wall fragments
__global__ void combine2_kernel(const float* __restrict__ Wq, const float* __restrict__ bq,
                                const float* __restrict__ Wc, const float* __restrict__ bcb,
                                ushort_t* __restrict__ Wall_arr, float* __restrict__ Wall_bias) {
    int tid = blockIdx.x * 256 + threadIdx.x;
    if (tid < 2304) {
        int l = tid / 1152, u = tid % 1152, k = u / 18, j = u % 18;
        float s = 0.f;
        if (j < 16) {
            int hh = j >> 3, d = j & 7;
            for (int c = 0; c < 64; ++c)
                s += Wq[l * 8192 + k * 128 + hh * 64 + c] * Wc[l * 1024 + d * 128 + hh * 64 + c];
        } else {
            int hh = j - 16;
            for (int c = 0; c < 64; ++c)
                s += Wq[l * 8192 + k * 128 + hh * 64 + c] * bcb[l * 128 + hh * 64 + c];
        }
        s *= 0.125f;
        int col = 448 + j;
        int ct = col >> 4, nn = col & 15;
        int kch = k >> 5, quad = (k >> 3) & 3, jj = k & 7;
        int ln = quad * 16 + nn;
        Wall_arr[(size_t)l * 32768 + ct * 1024 + kch * 512 + ln * 8 + jj] = f2bf(s);
    } else if (tid < 2304 + 36) {
        int u = tid - 2304;
        int l = u / 18, j = u % 18;
        float s = 0.f;
        if (j < 16) {
            int hh = j >> 3, d = j & 7;
            for (int c = 0; c < 64; ++c)
                s += bq[l * 128 + hh * 64 + c] * Wc[l * 1024 + d * 128 + hh * 64 + c];
        } else {
            int hh = j - 16;
            for (int c = 0; c < 64; ++c)
                s += bq[l * 128 + hh * 64 + c] * bcb[l * 128 + hh * 64 + c];
        }
        Wall_bias[l * 512 + 448 + j] = 0.125f * s;
    }
}

// ---------------- CSR build ----------------

__global__ void csr_count_kernel(const int* __restrict__ dst, int* __restrict__ counts, int E) {
    int e = blockIdx.x * 256 + threadIdx.x;
    if (e < E) atomicAdd(&counts[dst[e]], 1);
}

__global__ void scan1_kernel(const int* __restrict__ counts, int* __restrict__ rowptr,
                             int* __restrict__ bsums, int N) {
    __shared__ int s[256];
    int t = threadIdx.x, i = blockIdx.x * 256 + t;
    int v = (i < N) ? counts[i] : 0;
    s[t] = v;
    __syncthreads();
    for (int d = 1; d < 256; d <<= 1) {
        int x = (t >= d) ? s[t - d] : 0;
        __syncthreads();
        s[t] += x;
        __syncthreads();
    }
    if (i < N) rowptr[i] = s[t] - v;
    if (t == 255) bsums[blockIdx.x] = s[255];
}

__global__ void scan2_kernel(int* __restrict__ bsums, int nb) {
    __shared__ int s[256];
    int t = threadIdx.x;
    int v = (t < nb) ? bsums[t] : 0;
    s[t] = v;
    __syncthreads();
    for (int d = 1; d < 256; d <<= 1) {
        int x = (t >= d) ? s[t - d] : 0;
        __syncthreads();
        s[t] += x;
        __syncthreads();
    }
    if (t < nb) bsums[t] = s[t] - v;
}

__global__ void scan3_kernel(int* __restrict__ rowptr, const int* __restrict__ bsums,
                             int* __restrict__ cursor, int N, int E) {
    int i = blockIdx.x * 256 + threadIdx.x;
    if (i < N) {
        int r = rowptr[i] + bsums[i >> 8];
        rowptr[i] = r;
        cursor[i] = r;
    }
    if (i == 0) rowptr[N] = E;
}

__global__ void csr_fill_kernel(const int* __restrict__ dst, const int* __restrict__ src,
                                const float* __restrict__ edge_attr, int* __restrict__ cursor,
                                int* __restrict__ csr_src, float* __restrict__ ea_perm, int E) {
    int e = blockIdx.x * 256 + threadIdx.x;
    if (e < E) {
        int pos = atomicAdd(&cursor[dst[e]], 1);
        csr_src[pos] = src[e] * 768 + 256;
        float4 a0 = *(const float4*)(edge_attr + (size_t)e * 8);
        float4 a1 = *(const float4*)(edge_attr + (size_t)e * 8 + 4);
        *(float4*)(ea_perm + (size_t)pos * 8) = a0;
        *(float4*)(ea_perm + (size_t)pos * 8 + 4) = a1;
    }
}

// ---------------- per-layer MFMA GEMM: [16 x 64] @ [64 x 466] ----------------

__global__ __launch_bounds__(256) void qkv_mfma_kernel(
    const ushort_t* __restrict__ h_bf,
    const ushort_t* __restrict__ Wall_arr, const float* __restrict__ Wall_bias,
    ushort_t* __restrict__ qkv, float* __restrict__ outbuf, float* __restrict__ qcbuf, int N) {
    int wave = threadIdx.x >> 6, lane = threadIdx.x & 63;
    int quad = lane >> 4, nn = lane & 15;
    int n0 = blockIdx.x * 16;
    int node_a = n0 + nn;
    if (node_a >= N) node_a = N - 1;
    const ushort_t* ap = h_bf + (size_t)node_a * 64 + quad * 8;
    short8 a0 = *(const short8*)ap;
    short8 a1 = *(const short8*)(ap + 32);
    int ct_start = (wave < 2) ? wave * 8 : (16 + (wave - 2) * 7);
    int ct_cnt = (wave < 2) ? 8 : 7;
    for (int i = 0; i < ct_cnt; ++i) {
        int ct = ct_start + i;
        const ushort_t* bp = Wall_arr + (size_t)ct * 1024 + lane * 8;
        short8 b0 = *(const short8*)bp;
        short8 b1 = *(const short8*)(bp + 512);
        float4v c = {0.f, 0.f, 0.f, 0.f};
        c = __builtin_amdgcn_mfma_f32_16x16x32_bf16(a0, b0, c, 0, 0, 0);
        c = __builtin_amdgcn_mfma_f32_16x16x32_bf16(a1, b1, c, 0, 0, 0);
        int col = ct * 16 + nn;
        float bias = Wall_bias[col];
        if (col < 384) {
            int cm;
            if (col < 128) cm = col;
            else if (col < 256) { int cc = col - 128; cm = 128 + ((cc >> 1) << 2) + (cc & 1); }
            else { int cc = col - 256; cm = 128 + ((cc >> 1) << 2) + 2 + (cc & 1); }
            ushort_t* qp = qkv + (size_t)(n0 + quad * 4) * 384 + cm;
#pragma unroll
            for (int r = 0; r < 4; ++r)
                if (n0 + quad * 4 + r < N) qp[(size_t)r * 384] = f2bf(c[r] + bias);
        } else if (col < 448) {
            float* op = outbuf + (size_t)(n0 + quad * 4) * 64 + (col - 448 + 64);
#pragma unroll
            for (int r = 0; r < 4; ++r)
                if (n0 + quad * 4 + r < N) op[(size_t)r * 64] = c[r] + bias;
        } else if (col < 466) {
            float* qp2 = qcbuf + (size_t)(n0 + quad * 4) * 20 + (col - 448);
#pragma unroll
            for (int r = 0; r < 4; ++r)
                if (n0 + quad * 4 + r < N) qp2[(size_t)r * 20] = c[r] + bias;
        }
    }
}

// ---------------- attention + fused BN partial stats ----------------

__global__ __launch_bounds__(256) void attn_kernel(
    const ushort_t* __restrict__ qkv, const float* __restrict__ qcbuf,
    const int* __restrict__ csr_src, const float* __restrict__ ea_perm,
    const int* __restrict__ rowptr,
    const float* __restrict__ Wc, const float* __restrict__ bcb,
    float* __restrict__ outbuf, float* __restrict__ part, int N) {
    __shared__ float Wc_s[1024];
    __shared__ float bc_s[128];
    __shared__ float sred[4][64];
    int t = threadIdx.x;
    for (int i = t; i < 1024; i += 256) Wc_s[i] = Wc[i];
    if (t < 128) bc_s[t] = bcb[t];
    __syncthreads();
    int lane = t & 63, wid = t >> 6;
    int half = lane >> 5, l31 = lane & 31;
    const char* qkvb = (const char*)qkv;
    float sa0 = 0.f, sa1 = 0.f, sq0 = 0.f, sq1 = 0.f;  // BN stats (half==0 lanes)
    for (int n = blockIdx.x * 4 + wid; n < N; n += gridDim.x * 4) {
        int start = rowptr[n], end = rowptr[n + 1];
        float2* op = (float2*)(outbuf + (size_t)n * 64 + 2 * l31);
        if (end <= start) {
            if (half == 0) {
                float2 cur = *op;   // outbuf holds skip
                sa0 += cur.x; sq0 += cur.x * cur.x;
                sa1 += cur.y; sq1 += cur.y * cur.y;
            }
            continue;
        }
        unsigned qraw = *(const unsigned*)(qkvb + (size_t)n * 768 + 4 * lane);
        float qx = bfu_lo(qraw), qy = bfu_hi(qraw);
        const float4 qcA = *(const float4*)(qcbuf + (size_t)n * 20 + half * 8);
        const float4 qcB = *(const float4*)(qcbuf + (size_t)n * 20 + half * 8 + 4);
        float qb = qcbuf[(size_t)n * 20 + 16 + half];
        float lsum = 0.f, ax = 0.f, ay = 0.f;
        float4 se0 = {0.f, 0.f, 0.f, 0.f}, se1 = {0.f, 0.f, 0.f, 0.f};
        for (int seg = start; seg < end; seg += 64) {
            int segcnt = min(64, end - seg);
            int li = (lane < segcnt) ? lane : (segcnt - 1);
            int offL = csr_src[seg + li];
            uint2 kvc[4], kvn[4];
#pragma unroll
            for (int j = 0; j < 4; ++j) {
                int idx = (j < segcnt) ? j : (segcnt - 1);
                int o = __shfl(offL, idx);
                kvc[j] = *(const uint2*)(qkvb + (size_t)(unsigned)o + 8 * lane);
            }
            for (int base = 0; base < segcnt; base += 4) {
                int nb2 = base + 4;
                if (nb2 < segcnt) {
#pragma unroll
                    for (int j = 0; j < 4; ++j) {
                        int idx = (nb2 + j < segcnt) ? (nb2 + j) : (segcnt - 1);
                        int o = __shfl(offL, idx);
                        kvn[j] = *(const uint2*)(qkvb + (size_t)(unsigned)o + 8 * lane);
                    }
                }
                float4 a0[4], a1[4];
                float dt[4];
#pragma unroll
                for (int j = 0; j < 4; ++j) {
                    int gi = seg + base + ((base + j < segcnt) ? j : 0);
                    const float* eap = ea_perm + (size_t)gi * 8;
                    a0[j] = *(const float4*)eap;
                    a1[j] = *(const float4*)(eap + 4);
                    dt[j] = qx * bfu_lo(kvc[j].x) + qy * bfu_hi(kvc[j].x);
                }
#pragma unroll
                for (int m = 1; m <= 16; m <<= 1) {
#pragma unroll
                    for (int j = 0; j < 4; ++j) dt[j] += __shfl_xor(dt[j], m);
                }
#pragma unroll
                for (int j = 0; j < 4; ++j) {
                    float s0 = dt[j] * 0.125f
                        + qcA.x * a0[j].x + qcA.y * a0[j].y + qcA.z * a0[j].z + qcA.w * a0[j].w
                        + qcB.x * a1[j].x + qcB.y * a1[j].y + qcB.z * a1[j].z + qcB.w * a1[j].w
                        + qb;
                    float p = (base + j < segcnt) ? __expf(fmaxf(s0, -60.f)) : 0.f;
                    lsum += p;
                    ax += p * bfu_lo(kvc[j].y);
                    ay += p * bfu_hi(kvc[j].y);
                    se0.x += p * a0[j].x; se0.y += p * a0[j].y;
                    se0.z += p * a0[j].z; se0.w += p * a0[j].w;
                    se1.x += p * a1[j].x; se1.y += p * a1[j].y;
                    se1.z += p * a1[j].z; se1.w += p * a1[j].w;
                }
#pragma unroll
                for (int j = 0; j < 4; ++j) kvc[j] = kvn[j];
            }
        }
        int j0 = half * 64 + 2 * l31;
        float w0 = lsum * bc_s[j0], w1 = lsum * bc_s[j0 + 1];
        w0 += se0.x * Wc_s[0 * 128 + j0] + se0.y * Wc_s[1 * 128 + j0] +
              se0.z * Wc_s[2 * 128 + j0] + se0.w * Wc_s[3 * 128 + j0] +
              se1.x * Wc_s[4 * 128 + j0] + se1.y * Wc_s[5 * 128 + j0] +
              se1.z * Wc_s[6 * 128 + j0] + se1.w * Wc_s[7 * 128 + j0];
        w1 += se0.x * Wc_s[0 * 128 + j0 + 1] + se0.y * Wc_s[1 * 128 + j0 + 1] +
              se0.z * Wc_s[2 * 128 + j0 + 1] + se0.w * Wc_s[3 * 128 + j0 + 1] +
              se1.x * Wc_s[4 * 128 + j0 + 1] + se1.y * Wc_s[5 * 128 + j0 + 1] +
              se1.z * Wc_s[6 * 128 + j0 + 1] + se1.w * Wc_s[7 * 128 + j0 + 1];
        float inv = 1.f / lsum;
        float ox = (ax + w0) * inv, oy = (ay + w1) * inv;
        float px = __shfl_xor(ox, 32), py = __shfl_xor(oy, 32);
        ox = 0.5f * (ox + px);
        oy = 0.5f * (oy + py);
        if (half == 0) {
            float2 cur = *op;
            float fx = cur.x + ox, fy = cur.y + oy;
            *op = make_float2(fx, fy);
            sa0 += fx; sq0 += fx * fx;
            sa1 += fy; sq1 += fy * fy;
        }
    }
    // block reduce BN partials -> part[block*128 + {c, 64+c}]
    __syncthreads();
    if (half == 0) { sred[wid][2 * l31] = sa0; sred[wid][2 * l31 + 1] = sa1; }
    __syncthreads();
    if (t < 64) part[(size_t)blockIdx.x * 128 + t] =
        sred[0][t] + sred[1][t] + sred[2][t] + sred[3][t];
    __syncthreads();
    if (half == 0) { sred[wid][2 * l31] = sq0; sred[wid][2 * l31 + 1] = sq1; }
    __syncthreads();
    if (t < 64) part[(size_t)blockIdx.x * 128 + 64 + t] =
        sred[0][t] + sred[1][t] + sred[2][t] + sred[3][t];
}

// ---------------- BN reduce (one block per slot) + apply ----------------

__global__ __launch_bounds__(256) void bnreduce_kernel(const float* __restrict__ part,
                                                       float* __restrict__ bnsums) {
    int s = blockIdx.x;  // 0..127
    int t = threadIdx.x;
    float a = 0.f;
    for (int b = t; b < ATTN_BLOCKS; b += 256) a += part[(size_t)b * 128 + s];
    __shared__ float sh[256];
    sh[t] = a;
    __syncthreads();
    for (int d = 128; d; d >>= 1) {
        if (t < d) sh[t] += sh[t + d];
        __syncthreads();
    }
    if (t == 0) bnsums[s] = sh[0];
}

// BN apply (scale computed inline from raw sums) + leaky + residual; optional gate
__global__ __launch_bounds__(256) void bnapply_kernel(
    const float* __restrict__ outbuf, const float* __restrict__ bnsums,
    const float* __restrict__ gamma, const float* __restrict__ beta,
    const float* __restrict__ gate_W, const float* __restrict__ gate_b,
    float* __restrict__ h, ushort_t* __restrict__ h_bf,
    float* __restrict__ gatebuf, int do_pool, int N) {
    int idx = blockIdx.x * 256 + threadIdx.x;
    if (idx >= N * 64) return;
    int c = idx & 63, n = idx >> 6;
    float invN = 1.f / (float)N;
    float mean = bnsums[c] * invN;
    float var = bnsums[64 + c] * invN - mean * mean;
    float scale = gamma[c] * rsqrtf(var + 1e-5f);
    float shift = beta[c] - mean * scale;
    float o = outbuf[idx] * scale + shift;
    o = (o > 0.f) ? o : 0.01f * o;
    float hn = h[idx] + o;
    h[idx] = hn;
    h_bf[idx] = f2bf(hn);
    if (do_pool) {
        float g = hn * gate_W[c];
#pragma unroll
        for (int off = 32; off; off >>= 1) g += __shfl_xor(g, off);
        if (c == 0) gatebuf[n] = g + gate_b[0];
    }
}

// ---------------- pooling ----------------

__global__ __launch_bounds__(256) void pool_max_kernel(const float* __restrict__ gatebuf,
                                                       const int* __restrict__ batch,
                                                       float* __restrict__ m, int N) {
    int b = blockIdx.x;
    int lo = 0, hi = N;
    while (lo < hi) { int mid = (lo + hi) >> 1; if (batch[mid] < b) lo = mid + 1; else hi = mid; }
    int start = lo;
    lo = start; hi = N;
    while (lo < hi) { int mid = (lo + hi) >> 1; if (batch[mid] <= b) lo = mid + 1; else hi = mid; }
    int end = lo;
    int t = threadIdx.x, lane = t & 63, wid = t >> 6;
    __shared__ float sm[4];
    float mx = -1e30f;
    for (int n = start + t; n < end; n += 256) mx = fmaxf(mx, gatebuf[n]);
#pragma unroll
    for (int off = 32; off; off >>= 1) mx = fmaxf(mx, __shfl_xor(mx, off));
    if (lane == 0) sm[wid] = mx;
    __syncthreads();
    if (t == 0) m[b] = fmaxf(fmaxf(sm[0], sm[1]), fmaxf(sm[2], sm[3]));
}

__global__ __launch_bounds__(256) void pool_acc_kernel(
    const float* __restrict__ h, const float* __restrict__ gatebuf,
    const int* __restrict__ batch, const float* __restrict__ gmax,
    float* __restrict__ pacc, float* __restrict__ pden, int N) {
    int b = blockIdx.x >> 3, chunk = blockIdx.x & 7;
    int lo = 0, hi = N;
    while (lo < hi) { int mid = (lo + hi) >> 1; if (batch[mid] < b) lo = mid + 1; else hi = mid; }
    int start = lo;
    lo = start; hi = N;
    while (lo < hi) { int mid = (lo + hi) >> 1; if (batch[mid] <= b) lo = mid + 1; else hi = mid; }
    int end = lo;
    int lane = threadIdx.x & 63, wid = threadIdx.x >> 6;
    int gwid = chunk * 4 + wid;
    float mb = gmax[b];
    float acc = 0.f, den = 0.f;
    for (int n = start + gwid; n < end; n += 32) {
        float ge = __expf(gatebuf[n] - mb);
        acc += ge * h[(size_t)n * 64 + lane];
        den += ge;
    }
    __shared__ float sacc[4][64];
    __shared__ float sden[4];
    sacc[wid][lane] = acc;
    if (lane == 0) sden[wid] = den;
    __syncthreads();
    if (wid == 0) {
        pacc[(size_t)blockIdx.x * 64 + lane] =
            sacc[0][lane] + sacc[1][lane] + sacc[2][lane] + sacc[3][lane];
        if (lane == 0) pden[blockIdx.x] = sden[0] + sden[1] + sden[2] + sden[3];
    }
}

__global__ void pool_fin_kernel(const float* __restrict__ pacc, const float* __restrict__ pden,
                                const float* __restrict__ out_W, const float* __restrict__ out_b,
                                float* __restrict__ out) {
    int b = blockIdx.x, c = threadIdx.x;
    float pc = 0.f, dv = 0.f;
#pragma unroll
    for (int j = 0; j < 8; ++j) {
        pc += pacc[(size_t)(b * 8 + j) * 64 + c];
        dv += pden[b * 8 + j];
    }
    float s = pc * out_W[c];
#pragma unroll
    for (int off = 32; off; off >>= 1) s += __shfl_xor(s, off);
    if (c == 0) {
        if (dv <= 0.f) dv = 1.f;
        float v = s / dv + out_b[0];
        out[b] = 1.f / (1.f + __expf(-v));
    }
}

// ---------------- host ----------------

extern "C" void kernel_launch(void* const* d_in, const int* in_sizes, int n_in,
                              void* d_out, int out_size, void* d_ws, size_t ws_size,
                              hipStream_t stream) {
    const float* x         = (const float*)d_in[0];
    const float* edge_attr = (const float*)d_in[1];
    const int*   edge_src  = (const int*)d_in[2];
    const int*   edge_dst  = (const int*)d_in[3];
    const int*   batch     = (const int*)d_in[4];
    const float* node_W    = (const float*)d_in[5];
    const float* node_b    = (const float*)d_in[6];
    const float* edge_W    = (const float*)d_in[7];
    const float* edge_b    = (const float*)d_in[8];
    const float* Wq        = (const float*)d_in[9];
    const float* bq        = (const float*)d_in[10];
    const float* Wk        = (const float*)d_in[11];
    const float* bk        = (const float*)d_in[12];
    const float* Wv        = (const float*)d_in[13];
    const float* bv        = (const float*)d_in[14];
    const float* We        = (const float*)d_in[15];
    const float* be        = (const float*)d_in[16];
    const float* Wskip     = (const float*)d_in[17];
    const float* bskip     = (const float*)d_in[18];
    const float* gamma     = (const float*)d_in[19];
    const float* beta      = (const float*)d_in[20];
    const float* gate_W    = (const float*)d_in[21];
    const float* gate_b    = (const float*)d_in[22];
    const float* out_W     = (const float*)d_in[23];
    const float* out_b     = (const float*)d_in[24];
    float* out = (float*)d_out;

    const int N = in_sizes[0] / 16;
    const int E = in_sizes[2];

    char* ws = (char*)d_ws;
    size_t off = 0;
    auto alloc = [&](size_t bytes) {
        size_t o = off;
        off += (bytes + 255) & ~(size_t)255;
        return o;
    };
    float*    h        = (float*)(ws + alloc((size_t)N * 64 * 4));
    ushort_t* h_bf     = (ushort_t*)(ws + alloc((size_t)N * 64 * 2));
    ushort_t* qkv      = (ushort_t*)(ws + alloc((size_t)N * 384 * 2));
    float*    outbuf   = (float*)(ws + alloc((size_t)N * 64 * 4));
    float*    qcbuf    = (float*)(ws + alloc((size_t)N * 20 * 4));
    int*      rowptr   = (int*)(ws + alloc((size_t)(N + 1) * 4));
    int*      cursor   = (int*)(ws + alloc((size_t)N * 4));
    int*      counts   = (int*)(ws + alloc((size_t)N * 4));
    int*      bsums    = (int*)(ws + alloc(1024));
    int*      csr_src  = (int*)(ws + alloc((size_t)E * 4));
    float*    ea_perm  = (float*)(ws + alloc((size_t)E * 8 * 4));
    float*    Wc       = (float*)(ws + alloc(2 * 1024 * 4));
    float*    bcb      = (float*)(ws + alloc(2 * 128 * 4));
    ushort_t* Wall_arr = (ushort_t*)(ws + alloc(2 * 32768 * 2));
    float*    Wall_b   = (float*)(ws + alloc(2 * 512 * 4));
    float*    bnsums   = (float*)(ws + alloc(128 * 4));
    float*    gatebuf  = (float*)(ws + alloc((size_t)N * 4));
    float*    gmax     = (float*)(ws + alloc(64 * 4));
    float*    pacc     = (float*)(ws + alloc((size_t)ATTN_BLOCKS * 128 * 4));
    float*    pden     = (float*)(ws + alloc(512 * 4));
    if (off > ws_size) return;

    int O0 = (N * 64 + 255) / 256;
    int O1 = O0 + (N + 255) / 256;
    int O2 = O1 + 9;
    int O3 = O2 + 228;
    setup_kernel<<<O3, 256, 0, stream>>>(
        x, node_W, node_b, edge_W, edge_b, We, be, Wq, bq, Wk, bk, Wv, bv, Wskip, bskip,
        h, h_bf, counts, Wc, bcb, Wall_arr, Wall_b, O0, O1, O2, N);
    combine2_kernel<<<10, 256, 0, stream>>>(Wq, bq, Wc, bcb, Wall_arr, Wall_b);

    csr_count_kernel<<<(E + 255) / 256, 256, 0, stream>>>(edge_dst, counts, E);
    int nb = (N + 255) / 256;
    scan1_kernel<<<nb, 256, 0, stream>>>(counts, rowptr, bsums, N);
    scan2_kernel<<<1, 256, 0, stream>>>(bsums, nb);
    scan3_kernel<<<nb, 256, 0, stream>>>(rowptr, bsums, cursor, N, E);
    csr_fill_kernel<<<(E + 255) / 256, 256, 0, stream>>>(edge_dst, edge_src, edge_attr,
                                                         cursor, csr_src, ea_perm, E);

    for (int l = 0; l < 2; ++l) {
        qkv_mfma_kernel<<<(N + 15) / 16, 256, 0, stream>>>(
            h_bf, Wall_arr + (size_t)l * 32768, Wall_b + l * 512, qkv, outbuf, qcbuf, N);
        attn_kernel<<<ATTN_BLOCKS, 256, 0, stream>>>(qkv, qcbuf, csr_src, ea_perm,
                                                     rowptr, Wc + l * 1024,
                                                     bcb + l * 128, outbuf, pacc, N);
        bnreduce_kernel<<<128, 256, 0, stream>>>(pacc, bnsums);
        bnapply_kernel<<<(N * 64 + 255) / 256, 256, 0, stream>>>(
            outbuf, bnsums, gamma + l * 64, beta + l * 64, gate_W, gate_b,
            h, h_bf, gatebuf, (l == 1) ? 1 : 0, N);
    }

    pool_max_kernel<<<64, 256, 0, stream>>>(gatebuf, batch, gmax, N);
    pool_acc_kernel<<<512, 256, 0, stream>>>(h, gatebuf, batch, gmax, pacc, pden, N);
    pool_fin_kernel<<<64, 64, 0, stream>>>(pacc, pden, out_W, out_b, out);
}